// Round 1
// baseline (743.483 us; speedup 1.0000x reference)
//
#include <hip/hip_runtime.h>
#include <hip/hip_bf16.h>

#define NEG_SLOPE 0.2f
#define BN_EPS 1e-5f

// ---------- Layer 1 node transform: h1 = x @ W1, alpha_src/dst dots ----------
// grid = N blocks, 256 threads. head = tid>>6 (4 heads x 64 ch).
__global__ void k_node1(const float* __restrict__ x, const float* __restrict__ W1,
                        const float* __restrict__ asw, const float* __restrict__ adw,
                        float* __restrict__ h1, float* __restrict__ as1, float* __restrict__ ad1) {
    int n = blockIdx.x, j = threadIdx.x;
    float x0 = x[n * 2 + 0], x1 = x[n * 2 + 1];
    float h = fmaf(x0, W1[j], x1 * W1[256 + j]);
    h1[n * 256 + j] = h;
    float ps = h * asw[j], pd = h * adw[j];
    for (int o = 32; o; o >>= 1) { ps += __shfl_down(ps, o); pd += __shfl_down(pd, o); }
    if ((j & 63) == 0) { int head = j >> 6; as1[n * 4 + head] = ps; ad1[n * 4 + head] = pd; }
}

// ---------- CSR build ----------
__global__ void k_deg(const int* __restrict__ ei, int E, int E2, int* __restrict__ cnt) {
    int i = blockIdx.x * blockDim.x + threadIdx.x;
    if (i >= E2) return;
    int d = (i < E) ? ei[E + i] : (i - E);
    atomicAdd(&cnt[d], 1);
}

__global__ void k_scan1(const int* __restrict__ deg, int* __restrict__ rp,
                        int* __restrict__ bsums, int n) {
    __shared__ int s[1024];
    int i = blockIdx.x * 1024 + threadIdx.x;
    int v = (i < n) ? deg[i] : 0;
    s[threadIdx.x] = v;
    __syncthreads();
    for (int o = 1; o < 1024; o <<= 1) {
        int t = (threadIdx.x >= o) ? s[threadIdx.x - o] : 0;
        __syncthreads();
        s[threadIdx.x] += t;
        __syncthreads();
    }
    if (i < n) rp[i] = s[threadIdx.x] - v;   // exclusive
    if (threadIdx.x == 1023) bsums[blockIdx.x] = s[1023];
}

__global__ void k_scan2(int* __restrict__ bsums, int nb, int* __restrict__ rp, int n, int total) {
    int run = 0;
    for (int b = 0; b < nb; b++) { int t = bsums[b]; bsums[b] = run; run += t; }
    rp[n] = total;
}

__global__ void k_scan3(int* __restrict__ rp, const int* __restrict__ bsums, int n) {
    int i = blockIdx.x * 1024 + threadIdx.x;
    if (i < n) rp[i] += bsums[blockIdx.x];
}

__global__ void k_scatter(const int* __restrict__ ei, int E, int E2,
                          const int* __restrict__ rp, int* __restrict__ cur,
                          int* __restrict__ esrc) {
    int i = blockIdx.x * blockDim.x + threadIdx.x;
    if (i >= E2) return;
    int s, d;
    if (i < E) { s = ei[i]; d = ei[E + i]; } else { s = d = i - E; }
    int pos = rp[d] + atomicAdd(&cur[d], 1);
    esrc[pos] = s;
}

// ---------- Layer 1 aggregation (softmax over incoming edges) ----------
// grid = N blocks, 256 threads (head = tid>>6)
__global__ void k_agg1(const int* __restrict__ rp, const int* __restrict__ esrc,
                       const float* __restrict__ as1, const float* __restrict__ ad1,
                       const float* __restrict__ h1, const float* __restrict__ b1,
                       float* __restrict__ out1) {
    int n = blockIdx.x, j = threadIdx.x, head = j >> 6;
    int beg = rp[n], end = rp[n + 1];
    float ad = ad1[n * 4 + head];
    float m = -1e30f;
    for (int k = beg; k < end; k++) {
        int s = esrc[k];
        float ev = as1[s * 4 + head] + ad;
        ev = ev > 0.f ? ev : NEG_SLOPE * ev;
        m = fmaxf(m, ev);
    }
    float den = 0.f, acc = 0.f;
    for (int k = beg; k < end; k++) {
        int s = esrc[k];
        float ev = as1[s * 4 + head] + ad;
        ev = ev > 0.f ? ev : NEG_SLOPE * ev;
        float w = __expf(ev - m);
        den += w;
        acc = fmaf(w, h1[s * 256 + j], acc);
    }
    out1[n * 256 + j] = acc / (den + 1e-16f) + b1[j];
}

// ---------- BatchNorm stats / apply+ELU (generic over F = blockDim.x) ----------
__global__ void k_bnstats(const float* __restrict__ v, int N, int F,
                          float* __restrict__ sum, float* __restrict__ sq) {
    int j = threadIdx.x;
    int rows = (N + gridDim.x - 1) / gridDim.x;
    int r0 = blockIdx.x * rows, r1 = min(N, r0 + rows);
    float s = 0.f, q = 0.f;
    for (int r = r0; r < r1; r++) { float t = v[r * F + j]; s += t; q = fmaf(t, t, q); }
    atomicAdd(&sum[j], s);
    atomicAdd(&sq[j], q);
}

__global__ void k_bnelu(float* __restrict__ v, int N, int F,
                        const float* __restrict__ sum, const float* __restrict__ sq,
                        const float* __restrict__ gamma, const float* __restrict__ beta) {
    int i = blockIdx.x * blockDim.x + threadIdx.x;
    if (i >= N * F) return;
    int j = i % F;
    float mu = sum[j] / N;
    float var = sq[j] / N - mu * mu;
    float y = (v[i] - mu) * rsqrtf(var + BN_EPS) * gamma[j] + beta[j];
    v[i] = y > 0.f ? y : (__expf(y) - 1.0f);
}

// ---------- Layer 2 GEMM: g2[N,128] = x2[N,256] @ W2[256,128] ----------
__global__ void k_gemm2(const float* __restrict__ x2, const float* __restrict__ W2,
                        float* __restrict__ g2, int N) {
    __shared__ float xs[16][256];
    int n0 = blockIdx.x * 16, tid = threadIdx.x;
    #pragma unroll
    for (int t = 0; t < 16; t++) {
        int n = n0 + t;
        xs[t][tid] = (n < N) ? x2[n * 256 + tid] : 0.f;
    }
    __syncthreads();
    int c = tid & 127, rb = (tid >> 7) * 8;
    float acc[8] = {0.f, 0.f, 0.f, 0.f, 0.f, 0.f, 0.f, 0.f};
    for (int k = 0; k < 256; k++) {
        float w = W2[k * 128 + c];
        #pragma unroll
        for (int r = 0; r < 8; r++) acc[r] = fmaf(xs[rb + r][k], w, acc[r]);
    }
    #pragma unroll
    for (int r = 0; r < 8; r++) {
        int n = n0 + rb + r;
        if (n < N) g2[n * 128 + c] = acc[r];
    }
}

// alpha dots for layer 2: one wave per node
__global__ void k_alpha2(const float* __restrict__ g2, const float* __restrict__ asw,
                         const float* __restrict__ adw, float* __restrict__ as2,
                         float* __restrict__ ad2) {
    int n = blockIdx.x, l = threadIdx.x;  // 64 threads
    float g0 = g2[n * 128 + l], g1 = g2[n * 128 + 64 + l];
    float ps = fmaf(g0, asw[l], g1 * asw[64 + l]);
    float pd = fmaf(g0, adw[l], g1 * adw[64 + l]);
    for (int o = 32; o; o >>= 1) { ps += __shfl_down(ps, o); pd += __shfl_down(pd, o); }
    if (l == 0) { as2[n] = ps; ad2[n] = pd; }
}

// ---------- Layer 2 aggregation ----------
__global__ void k_agg2(const int* __restrict__ rp, const int* __restrict__ esrc,
                       const float* __restrict__ as2, const float* __restrict__ ad2,
                       const float* __restrict__ g2, const float* __restrict__ b2,
                       float* __restrict__ out2) {
    int n = blockIdx.x, j = threadIdx.x;  // 128 threads
    int beg = rp[n], end = rp[n + 1];
    float ad = ad2[n];
    float m = -1e30f;
    for (int k = beg; k < end; k++) {
        int s = esrc[k];
        float ev = as2[s] + ad;
        ev = ev > 0.f ? ev : NEG_SLOPE * ev;
        m = fmaxf(m, ev);
    }
    float den = 0.f, acc = 0.f;
    for (int k = beg; k < end; k++) {
        int s = esrc[k];
        float ev = as2[s] + ad;
        ev = ev > 0.f ? ev : NEG_SLOPE * ev;
        float w = __expf(ev - m);
        den += w;
        acc = fmaf(w, g2[s * 128 + j], acc);
    }
    out2[n * 128 + j] = acc / (den + 1e-16f) + b2[j];
}

// ---------- Pooling ----------
__global__ void k_count(const int* __restrict__ batch, float* __restrict__ counts, int N) {
    int i = blockIdx.x * blockDim.x + threadIdx.x;
    if (i < N) atomicAdd(&counts[batch[i]], 1.0f);
}

__global__ void k_pool(const float* __restrict__ v, const int* __restrict__ batch,
                       float* __restrict__ out, int N) {
    int j = threadIdx.x;  // 128
    int rows = (N + gridDim.x - 1) / gridDim.x;
    int r0 = blockIdx.x * rows, r1 = min(N, r0 + rows);
    int curg = -1;
    float acc = 0.f;
    for (int r = r0; r < r1; r++) {
        int g = batch[r];
        if (g != curg) {
            if (curg >= 0) atomicAdd(&out[curg * 128 + j], acc);
            curg = g; acc = 0.f;
        }
        acc += v[r * 128 + j];
    }
    if (curg >= 0) atomicAdd(&out[curg * 128 + j], acc);
}

__global__ void k_div(float* __restrict__ out, const float* __restrict__ counts) {
    int g = blockIdx.x, j = threadIdx.x;
    out[g * 128 + j] /= fmaxf(counts[g], 1.0f);
}

extern "C" void kernel_launch(void* const* d_in, const int* in_sizes, int n_in,
                              void* d_out, int out_size, void* d_ws, size_t ws_size,
                              hipStream_t stream) {
    const float* x     = (const float*)d_in[0];
    const int*   ei    = (const int*)d_in[1];
    const int*   batch = (const int*)d_in[2];
    const float* W1    = (const float*)d_in[4];
    const float* asw1  = (const float*)d_in[5];
    const float* adw1  = (const float*)d_in[6];
    const float* b1    = (const float*)d_in[7];
    const float* gamma1= (const float*)d_in[8];
    const float* beta1 = (const float*)d_in[9];
    const float* W2    = (const float*)d_in[10];
    const float* asw2  = (const float*)d_in[11];
    const float* adw2  = (const float*)d_in[12];
    const float* b2    = (const float*)d_in[13];
    const float* gamma2= (const float*)d_in[14];
    const float* beta2 = (const float*)d_in[15];
    float* out = (float*)d_out;

    const int N  = in_sizes[2];
    const int E  = in_sizes[1] / 2;
    const int E2 = E + N;
    const int G  = out_size / 128;

    char* ws = (char*)d_ws;
    size_t off = 0;
    auto A = [&](size_t bytes) { size_t o = off; off += (bytes + 255) & ~(size_t)255; return o; };
    float* h1    = (float*)(ws + A((size_t)N * 256 * 4));  // reused as g2 (N*128)
    float* out1  = (float*)(ws + A((size_t)N * 256 * 4));  // reused as x2, then out2 (N*128)
    float* as1   = (float*)(ws + A((size_t)N * 4 * 4));
    float* ad1   = (float*)(ws + A((size_t)N * 4 * 4));
    float* as2   = (float*)(ws + A((size_t)N * 4));
    float* ad2   = (float*)(ws + A((size_t)N * 4));
    float* bnsum = (float*)(ws + A(256 * 4));
    float* bnsq  = (float*)(ws + A(256 * 4));
    float* counts= (float*)(ws + A((size_t)G * 4));
    int*   rp    = (int*)(ws + A((size_t)(N + 1) * 4));
    int*   cnt   = (int*)(ws + A((size_t)N * 4));
    int*   esrc  = (int*)(ws + A((size_t)E2 * 4));
    int*   bsums = (int*)(ws + A((size_t)((N + 1023) / 1024) * 4));
    float* g2   = h1;    // layer-2 features reuse h1's buffer
    float* out2 = out1;  // layer-2 aggregate reuses out1's buffer

    const int nb = (N + 1023) / 1024;

    // Layer 1 node transform
    k_node1<<<N, 256, 0, stream>>>(x, W1, asw1, adw1, h1, as1, ad1);

    // CSR build (dst-keyed)
    hipMemsetAsync(cnt, 0, (size_t)N * 4, stream);
    k_deg<<<(E2 + 255) / 256, 256, 0, stream>>>(ei, E, E2, cnt);
    k_scan1<<<nb, 1024, 0, stream>>>(cnt, rp, bsums, N);
    k_scan2<<<1, 1, 0, stream>>>(bsums, nb, rp, N, E2);
    k_scan3<<<nb, 1024, 0, stream>>>(rp, bsums, N);
    hipMemsetAsync(cnt, 0, (size_t)N * 4, stream);
    k_scatter<<<(E2 + 255) / 256, 256, 0, stream>>>(ei, E, E2, rp, cnt, esrc);

    // Layer 1 aggregation + bias
    k_agg1<<<N, 256, 0, stream>>>(rp, esrc, as1, ad1, h1, b1, out1);

    // BN1 + ELU (in place -> x2)
    hipMemsetAsync(bnsum, 0, 256 * 4, stream);
    hipMemsetAsync(bnsq, 0, 256 * 4, stream);
    k_bnstats<<<256, 256, 0, stream>>>(out1, N, 256, bnsum, bnsq);
    k_bnelu<<<(N * 256 + 255) / 256, 256, 0, stream>>>(out1, N, 256, bnsum, bnsq, gamma1, beta1);

    // Layer 2 GEMM + alpha dots
    k_gemm2<<<(N + 15) / 16, 256, 0, stream>>>(out1, W2, g2, N);
    k_alpha2<<<N, 64, 0, stream>>>(g2, asw2, adw2, as2, ad2);

    // Layer 2 aggregation + bias
    k_agg2<<<N, 128, 0, stream>>>(rp, esrc, as2, ad2, g2, b2, out2);

    // BN2 + ELU (in place)
    hipMemsetAsync(bnsum, 0, 256 * 4, stream);
    hipMemsetAsync(bnsq, 0, 256 * 4, stream);
    k_bnstats<<<256, 128, 0, stream>>>(out2, N, 128, bnsum, bnsq);
    k_bnelu<<<(N * 128 + 255) / 256, 256, 0, stream>>>(out2, N, 128, bnsum, bnsq, gamma2, beta2);

    // Global mean pool
    hipMemsetAsync(out, 0, (size_t)G * 128 * 4, stream);
    hipMemsetAsync(counts, 0, (size_t)G * 4, stream);
    k_count<<<(N + 255) / 256, 256, 0, stream>>>(batch, counts, N);
    k_pool<<<256, 128, 0, stream>>>(out2, batch, out, N);
    k_div<<<G, 128, 0, stream>>>(out, counts);
}

// Round 2
// 493.221 us; speedup vs baseline: 1.5074x; 1.5074x over previous
//
#include <hip/hip_runtime.h>
#include <hip/hip_bf16.h>

#define NEG_SLOPE 0.2f
#define BN_EPS 1e-5f

// ---------- tiny coefficient kernel: fold att vectors through W1 ----------
// coef[h*4+0] = sum_j W1[0,h*64+c]*a_src[h*64+c]  (cs0)
// coef[h*4+1] = cs1 (W1 row 1), +2 = cd0, +3 = cd1
__global__ void k_coef(const float* __restrict__ W1, const float* __restrict__ asw,
                       const float* __restrict__ adw, float* __restrict__ coef) {
    int j = threadIdx.x;  // 256
    float w0 = W1[j], w1 = W1[256 + j], as = asw[j], ad = adw[j];
    float v0 = w0 * as, v1 = w1 * as, v2 = w0 * ad, v3 = w1 * ad;
    for (int o = 32; o; o >>= 1) {
        v0 += __shfl_down(v0, o); v1 += __shfl_down(v1, o);
        v2 += __shfl_down(v2, o); v3 += __shfl_down(v3, o);
    }
    if ((j & 63) == 0) {
        int h = j >> 6;
        coef[h * 4 + 0] = v0; coef[h * 4 + 1] = v1;
        coef[h * 4 + 2] = v2; coef[h * 4 + 3] = v3;
    }
}

// ---------- CSR build ----------
__global__ void k_deg(const int* __restrict__ ei, int E, int E2, int* __restrict__ cnt) {
    int i = blockIdx.x * blockDim.x + threadIdx.x;
    if (i >= E2) return;
    int d = (i < E) ? ei[E + i] : (i - E);
    atomicAdd(&cnt[d], 1);
}

__global__ void k_scan1(const int* __restrict__ deg, int* __restrict__ rp,
                        int* __restrict__ bsums, int n) {
    __shared__ int s[1024];
    int i = blockIdx.x * 1024 + threadIdx.x;
    int v = (i < n) ? deg[i] : 0;
    s[threadIdx.x] = v;
    __syncthreads();
    for (int o = 1; o < 1024; o <<= 1) {
        int t = (threadIdx.x >= o) ? s[threadIdx.x - o] : 0;
        __syncthreads();
        s[threadIdx.x] += t;
        __syncthreads();
    }
    if (i < n) rp[i] = s[threadIdx.x] - v;
    if (threadIdx.x == 1023) bsums[blockIdx.x] = s[1023];
}

__global__ void k_scan2(int* __restrict__ bsums, int nb, int* __restrict__ rp, int n, int total) {
    int run = 0;
    for (int b = 0; b < nb; b++) { int t = bsums[b]; bsums[b] = run; run += t; }
    rp[n] = total;
}

__global__ void k_scan3(int* __restrict__ rp, const int* __restrict__ bsums, int n) {
    int i = blockIdx.x * 1024 + threadIdx.x;
    if (i < n) rp[i] += bsums[blockIdx.x];
}

__global__ void k_scatter(const int* __restrict__ ei, int E, int E2,
                          const int* __restrict__ rp, int* __restrict__ cur,
                          int* __restrict__ esrc) {
    int i = blockIdx.x * blockDim.x + threadIdx.x;
    if (i >= E2) return;
    int s, d;
    if (i < E) { s = ei[i]; d = ei[E + i]; } else { s = d = i - E; }
    int pos = rp[d] + atomicAdd(&cur[d], 1);
    esrc[pos] = s;
}

// ---------- Layer 1 aggregation, rank-2 form: one THREAD per node ----------
// out per node: sx[4], sy[4], den[4]  (weighted sums of x0,x1 per head)
__global__ void k_agg1r(const int* __restrict__ rp, const int* __restrict__ esrc,
                        const float* __restrict__ x, const float* __restrict__ coef,
                        float* __restrict__ sxy, int N) {
    int n = blockIdx.x * blockDim.x + threadIdx.x;
    if (n >= N) return;
    float c[16];
    #pragma unroll
    for (int i = 0; i < 16; i++) c[i] = coef[i];
    float x0n = x[2 * n], x1n = x[2 * n + 1];
    float ad[4], den[4], sx[4], sy[4];
    #pragma unroll
    for (int h = 0; h < 4; h++) {
        ad[h] = fmaf(x0n, c[h * 4 + 2], x1n * c[h * 4 + 3]);
        den[h] = 0.f; sx[h] = 0.f; sy[h] = 0.f;
    }
    int beg = rp[n], end = rp[n + 1];
    for (int k = beg; k < end; k++) {
        int s = esrc[k];
        float xs0 = x[2 * s], xs1 = x[2 * s + 1];
        #pragma unroll
        for (int h = 0; h < 4; h++) {
            float e = fmaf(xs0, c[h * 4 + 0], xs1 * c[h * 4 + 1]) + ad[h];
            e = e > 0.f ? e : NEG_SLOPE * e;
            float w = __expf(e);
            den[h] += w; sx[h] = fmaf(w, xs0, sx[h]); sy[h] = fmaf(w, xs1, sy[h]);
        }
    }
    float* o = sxy + (size_t)n * 12;
    #pragma unroll
    for (int h = 0; h < 4; h++) { o[h] = sx[h]; o[4 + h] = sy[h]; o[8 + h] = den[h]; }
}

// ---------- Layer 1 epilogue: out1 = rank-2 reconstruct + bias; fused BN1 stats ----------
__global__ void k_out1(const float* __restrict__ sxy, const float* __restrict__ W1,
                       const float* __restrict__ b1, float* __restrict__ out1,
                       float* __restrict__ bnsum, float* __restrict__ bnsq, int N) {
    int j = threadIdx.x;  // 256, channel
    int h = j >> 6;
    float w0 = W1[j], w1 = W1[256 + j], bb = b1[j];
    int rows = (N + gridDim.x - 1) / gridDim.x;
    int r0 = blockIdx.x * rows, r1 = min(N, r0 + rows);
    float s = 0.f, q = 0.f;
    for (int r = r0; r < r1; r++) {
        const float* p = sxy + (size_t)r * 12;
        float sx = p[h], sy = p[4 + h], dn = p[8 + h];
        float t = fmaf(sx, w0, sy * w1) / (dn + 1e-16f) + bb;
        out1[(size_t)r * 256 + j] = t;
        s += t; q = fmaf(t, t, q);
    }
    atomicAdd(&bnsum[j], s);
    atomicAdd(&bnsq[j], q);
}

// ---------- Layer 2 GEMM with fused BN1+ELU on load ----------
__global__ void k_gemm2(const float* __restrict__ x2raw, const float* __restrict__ W2,
                        const float* __restrict__ bnsum, const float* __restrict__ bnsq,
                        const float* __restrict__ gamma, const float* __restrict__ beta,
                        float* __restrict__ g2, int N) {
    __shared__ float xs[16][256];
    int n0 = blockIdx.x * 16, tid = threadIdx.x;
    float mu = bnsum[tid] / N;
    float var = bnsq[tid] / N - mu * mu;
    float sc = rsqrtf(var + BN_EPS) * gamma[tid];
    float sh = beta[tid] - mu * sc;
    #pragma unroll
    for (int t = 0; t < 16; t++) {
        int n = n0 + t;
        float v = 0.f;
        if (n < N) {
            float y = fmaf(x2raw[(size_t)n * 256 + tid], sc, sh);
            v = y > 0.f ? y : (__expf(y) - 1.0f);
        }
        xs[t][tid] = v;
    }
    __syncthreads();
    int c = tid & 127, rb = (tid >> 7) * 8;
    float acc[8] = {0.f, 0.f, 0.f, 0.f, 0.f, 0.f, 0.f, 0.f};
    for (int k = 0; k < 256; k++) {
        float w = W2[k * 128 + c];
        #pragma unroll
        for (int r = 0; r < 8; r++) acc[r] = fmaf(xs[rb + r][k], w, acc[r]);
    }
    #pragma unroll
    for (int r = 0; r < 8; r++) {
        int n = n0 + rb + r;
        if (n < N) g2[(size_t)n * 128 + c] = acc[r];
    }
}

// alpha dots for layer 2: one wave per node
__global__ void k_alpha2(const float* __restrict__ g2, const float* __restrict__ asw,
                         const float* __restrict__ adw, float* __restrict__ as2,
                         float* __restrict__ ad2) {
    int n = blockIdx.x, l = threadIdx.x;  // 64 threads
    float g0 = g2[(size_t)n * 128 + l], g1 = g2[(size_t)n * 128 + 64 + l];
    float ps = fmaf(g0, asw[l], g1 * asw[64 + l]);
    float pd = fmaf(g0, adw[l], g1 * adw[64 + l]);
    for (int o = 32; o; o >>= 1) { ps += __shfl_down(ps, o); pd += __shfl_down(pd, o); }
    if (l == 0) { as2[n] = ps; ad2[n] = pd; }
}

// ---------- Layer 2 aggregation: weights staged in LDS, single pass ----------
__global__ void k_agg2(const int* __restrict__ rp, const int* __restrict__ esrc,
                       const float* __restrict__ as2, const float* __restrict__ ad2,
                       const float* __restrict__ g2, const float* __restrict__ b2,
                       float* __restrict__ out2) {
    __shared__ float ws[128];
    __shared__ int ssn[128];
    int n = blockIdx.x, j = threadIdx.x;  // 128 threads
    int beg = rp[n], end = rp[n + 1];
    float ad = ad2[n];
    float acc = 0.f, den = 0.f;
    for (int t0 = beg; t0 < end; t0 += 128) {
        int k = t0 + j;
        if (k < end) {
            int s = esrc[k];
            float e = as2[s] + ad;
            e = e > 0.f ? e : NEG_SLOPE * e;
            ws[j] = __expf(e);
            ssn[j] = s;
        }
        __syncthreads();
        int nt = min(128, end - t0);
        for (int k2 = 0; k2 < nt; k2++) {
            float w = ws[k2];
            den += w;
            acc = fmaf(w, g2[(size_t)ssn[k2] * 128 + j], acc);
        }
        __syncthreads();
    }
    out2[(size_t)n * 128 + j] = acc / (den + 1e-16f) + b2[j];
}

// ---------- BN stats (generic over F = blockDim.x) ----------
__global__ void k_bnstats(const float* __restrict__ v, int N, int F,
                          float* __restrict__ sum, float* __restrict__ sq) {
    int j = threadIdx.x;
    int rows = (N + gridDim.x - 1) / gridDim.x;
    int r0 = blockIdx.x * rows, r1 = min(N, r0 + rows);
    float s = 0.f, q = 0.f;
    for (int r = r0; r < r1; r++) { float t = v[(size_t)r * F + j]; s += t; q = fmaf(t, t, q); }
    atomicAdd(&sum[j], s);
    atomicAdd(&sq[j], q);
}

// ---------- Pooling with fused BN2+ELU ----------
__global__ void k_count(const int* __restrict__ batch, float* __restrict__ counts, int N) {
    int i = blockIdx.x * blockDim.x + threadIdx.x;
    if (i < N) atomicAdd(&counts[batch[i]], 1.0f);
}

__global__ void k_poolbn(const float* __restrict__ v, const int* __restrict__ batch,
                         const float* __restrict__ bnsum, const float* __restrict__ bnsq,
                         const float* __restrict__ gamma, const float* __restrict__ beta,
                         float* __restrict__ out, int N) {
    int j = threadIdx.x;  // 128
    float mu = bnsum[j] / N;
    float var = bnsq[j] / N - mu * mu;
    float sc = rsqrtf(var + BN_EPS) * gamma[j];
    float sh = beta[j] - mu * sc;
    int rows = (N + gridDim.x - 1) / gridDim.x;
    int r0 = blockIdx.x * rows, r1 = min(N, r0 + rows);
    int curg = -1;
    float acc = 0.f;
    for (int r = r0; r < r1; r++) {
        int g = batch[r];
        if (g != curg) {
            if (curg >= 0) atomicAdd(&out[curg * 128 + j], acc);
            curg = g; acc = 0.f;
        }
        float y = fmaf(v[(size_t)r * 128 + j], sc, sh);
        acc += y > 0.f ? y : (__expf(y) - 1.0f);
    }
    if (curg >= 0) atomicAdd(&out[curg * 128 + j], acc);
}

__global__ void k_div(float* __restrict__ out, const float* __restrict__ counts) {
    int g = blockIdx.x, j = threadIdx.x;
    out[g * 128 + j] /= fmaxf(counts[g], 1.0f);
}

extern "C" void kernel_launch(void* const* d_in, const int* in_sizes, int n_in,
                              void* d_out, int out_size, void* d_ws, size_t ws_size,
                              hipStream_t stream) {
    const float* x     = (const float*)d_in[0];
    const int*   ei    = (const int*)d_in[1];
    const int*   batch = (const int*)d_in[2];
    const float* W1    = (const float*)d_in[4];
    const float* asw1  = (const float*)d_in[5];
    const float* adw1  = (const float*)d_in[6];
    const float* b1    = (const float*)d_in[7];
    const float* gamma1= (const float*)d_in[8];
    const float* beta1 = (const float*)d_in[9];
    const float* W2    = (const float*)d_in[10];
    const float* asw2  = (const float*)d_in[11];
    const float* adw2  = (const float*)d_in[12];
    const float* b2    = (const float*)d_in[13];
    const float* gamma2= (const float*)d_in[14];
    const float* beta2 = (const float*)d_in[15];
    float* out = (float*)d_out;

    const int N  = in_sizes[2];
    const int E  = in_sizes[1] / 2;
    const int E2 = E + N;
    const int G  = out_size / 128;

    char* ws = (char*)d_ws;
    size_t off = 0;
    auto A = [&](size_t bytes) { size_t o = off; off += (bytes + 255) & ~(size_t)255; return o; };
    float* out1  = (float*)(ws + A((size_t)N * 256 * 4));   // raw (pre-BN) layer-1 output
    float* g2    = (float*)(ws + A((size_t)N * 128 * 4));   // layer-2 features
    float* out2  = (float*)(ws + A((size_t)N * 128 * 4));   // raw (pre-BN) layer-2 output
    float* sxy   = (float*)(ws + A((size_t)N * 12 * 4));
    float* as2   = (float*)(ws + A((size_t)N * 4));
    float* ad2   = (float*)(ws + A((size_t)N * 4));
    float* coef  = (float*)(ws + A(16 * 4));
    float* bnsum = (float*)(ws + A(256 * 4));
    float* bnsq  = (float*)(ws + A(256 * 4));
    float* counts= (float*)(ws + A((size_t)G * 4));
    int*   rp    = (int*)(ws + A((size_t)(N + 1) * 4));
    int*   cnt   = (int*)(ws + A((size_t)N * 4));
    int*   esrc  = (int*)(ws + A((size_t)E2 * 4));
    int*   bsums = (int*)(ws + A((size_t)((N + 1023) / 1024) * 4));

    const int nb = (N + 1023) / 1024;

    // fold attention vectors through W1 (tiny)
    k_coef<<<1, 256, 0, stream>>>(W1, asw1, adw1, coef);

    // CSR build (dst-keyed)
    hipMemsetAsync(cnt, 0, (size_t)N * 4, stream);
    k_deg<<<(E2 + 255) / 256, 256, 0, stream>>>(ei, E, E2, cnt);
    k_scan1<<<nb, 1024, 0, stream>>>(cnt, rp, bsums, N);
    k_scan2<<<1, 1, 0, stream>>>(bsums, nb, rp, N, E2);
    k_scan3<<<nb, 1024, 0, stream>>>(rp, bsums, N);
    hipMemsetAsync(cnt, 0, (size_t)N * 4, stream);
    k_scatter<<<(E2 + 255) / 256, 256, 0, stream>>>(ei, E, E2, rp, cnt, esrc);

    // Layer 1: rank-2 aggregation (thread per node), then epilogue + BN1 stats
    k_agg1r<<<(N + 255) / 256, 256, 0, stream>>>(rp, esrc, x, coef, sxy, N);
    hipMemsetAsync(bnsum, 0, 256 * 4, stream);
    hipMemsetAsync(bnsq, 0, 256 * 4, stream);
    k_out1<<<256, 256, 0, stream>>>(sxy, W1, b1, out1, bnsum, bnsq, N);

    // Layer 2 GEMM (BN1+ELU fused on load) + alpha dots
    k_gemm2<<<(N + 15) / 16, 256, 0, stream>>>(out1, W2, bnsum, bnsq, gamma1, beta1, g2, N);
    k_alpha2<<<N, 64, 0, stream>>>(g2, asw2, adw2, as2, ad2);

    // Layer 2 aggregation
    k_agg2<<<N, 128, 0, stream>>>(rp, esrc, as2, ad2, g2, b2, out2);

    // BN2 stats, then pooling with fused BN2+ELU
    hipMemsetAsync(bnsum, 0, 256 * 4, stream);
    hipMemsetAsync(bnsq, 0, 256 * 4, stream);
    k_bnstats<<<256, 128, 0, stream>>>(out2, N, 128, bnsum, bnsq);

    hipMemsetAsync(out, 0, (size_t)G * 128 * 4, stream);
    hipMemsetAsync(counts, 0, (size_t)G * 4, stream);
    k_count<<<(N + 255) / 256, 256, 0, stream>>>(batch, counts, N);
    k_poolbn<<<256, 128, 0, stream>>>(out2, batch, bnsum, bnsq, gamma2, beta2, out, N);
    k_div<<<G, 128, 0, stream>>>(out, counts);
}

// Round 3
// 423.285 us; speedup vs baseline: 1.7565x; 1.1652x over previous
//
#include <hip/hip_runtime.h>
#include <hip/hip_bf16.h>

#define NEG_SLOPE 0.2f
#define BN_EPS 1e-5f

// ---------- tiny coefficient kernel: fold att vectors through W1 ----------
__global__ void k_coef(const float* __restrict__ W1, const float* __restrict__ asw,
                       const float* __restrict__ adw, float* __restrict__ coef) {
    int j = threadIdx.x;  // 256
    float w0 = W1[j], w1 = W1[256 + j], as = asw[j], ad = adw[j];
    float v0 = w0 * as, v1 = w1 * as, v2 = w0 * ad, v3 = w1 * ad;
    for (int o = 32; o; o >>= 1) {
        v0 += __shfl_down(v0, o); v1 += __shfl_down(v1, o);
        v2 += __shfl_down(v2, o); v3 += __shfl_down(v3, o);
    }
    if ((j & 63) == 0) {
        int h = j >> 6;
        coef[h * 4 + 0] = v0; coef[h * 4 + 1] = v1;
        coef[h * 4 + 2] = v2; coef[h * 4 + 3] = v3;
    }
}

// ---------- CSR build ----------
__global__ void k_deg(const int* __restrict__ ei, int E, int E2, int* __restrict__ cnt) {
    int i = blockIdx.x * blockDim.x + threadIdx.x;
    if (i >= E2) return;
    int d = (i < E) ? ei[E + i] : (i - E);
    atomicAdd(&cnt[d], 1);
}

__global__ void k_scan1(const int* __restrict__ deg, int* __restrict__ rp,
                        int* __restrict__ bsums, int n) {
    __shared__ int s[1024];
    int i = blockIdx.x * 1024 + threadIdx.x;
    int v = (i < n) ? deg[i] : 0;
    s[threadIdx.x] = v;
    __syncthreads();
    for (int o = 1; o < 1024; o <<= 1) {
        int t = (threadIdx.x >= o) ? s[threadIdx.x - o] : 0;
        __syncthreads();
        s[threadIdx.x] += t;
        __syncthreads();
    }
    if (i < n) rp[i] = s[threadIdx.x] - v;
    if (threadIdx.x == 1023) bsums[blockIdx.x] = s[1023];
}

__global__ void k_scan2(int* __restrict__ bsums, int nb, int* __restrict__ rp, int n, int total) {
    int run = 0;
    for (int b = 0; b < nb; b++) { int t = bsums[b]; bsums[b] = run; run += t; }
    rp[n] = total;
}

__global__ void k_scan3(int* __restrict__ rp, const int* __restrict__ bsums, int n) {
    int i = blockIdx.x * 1024 + threadIdx.x;
    if (i < n) rp[i] += bsums[blockIdx.x];
}

__global__ void k_scatter(const int* __restrict__ ei, int E, int E2,
                          const int* __restrict__ rp, int* __restrict__ cur,
                          int* __restrict__ esrc) {
    int i = blockIdx.x * blockDim.x + threadIdx.x;
    if (i >= E2) return;
    int s, d;
    if (i < E) { s = ei[i]; d = ei[E + i]; } else { s = d = i - E; }
    int pos = rp[d] + atomicAdd(&cur[d], 1);
    esrc[pos] = s;
}

// ---------- Layer 1 aggregation, rank-2 form: one THREAD per node ----------
__global__ void k_agg1r(const int* __restrict__ rp, const int* __restrict__ esrc,
                        const float* __restrict__ x, const float* __restrict__ coef,
                        float* __restrict__ sxy, int N) {
    int n = blockIdx.x * blockDim.x + threadIdx.x;
    if (n >= N) return;
    float c[16];
    #pragma unroll
    for (int i = 0; i < 16; i++) c[i] = coef[i];
    float x0n = x[2 * n], x1n = x[2 * n + 1];
    float ad[4], den[4], sx[4], sy[4];
    #pragma unroll
    for (int h = 0; h < 4; h++) {
        ad[h] = fmaf(x0n, c[h * 4 + 2], x1n * c[h * 4 + 3]);
        den[h] = 0.f; sx[h] = 0.f; sy[h] = 0.f;
    }
    int beg = rp[n], end = rp[n + 1];
    for (int k = beg; k < end; k++) {
        int s = esrc[k];
        float xs0 = x[2 * s], xs1 = x[2 * s + 1];
        #pragma unroll
        for (int h = 0; h < 4; h++) {
            float e = fmaf(xs0, c[h * 4 + 0], xs1 * c[h * 4 + 1]) + ad[h];
            e = e > 0.f ? e : NEG_SLOPE * e;
            float w = __expf(e);
            den[h] += w; sx[h] = fmaf(w, xs0, sx[h]); sy[h] = fmaf(w, xs1, sy[h]);
        }
    }
    float* o = sxy + (size_t)n * 12;
    #pragma unroll
    for (int h = 0; h < 4; h++) { o[h] = sx[h]; o[4 + h] = sy[h]; o[8 + h] = den[h]; }
}

// ---------- Layer 1 epilogue: rank-2 reconstruct + bias; fused BN1 stats ----------
__global__ void k_out1(const float* __restrict__ sxy, const float* __restrict__ W1,
                       const float* __restrict__ b1, float* __restrict__ out1,
                       float* __restrict__ bnsum, float* __restrict__ bnsq, int N) {
    int j = threadIdx.x;  // 256, channel
    int h = j >> 6;
    float w0 = W1[j], w1 = W1[256 + j], bb = b1[j];
    int rows = (N + gridDim.x - 1) / gridDim.x;
    int r0 = blockIdx.x * rows, r1 = min(N, r0 + rows);
    float s = 0.f, q = 0.f;
    for (int r = r0; r < r1; r++) {
        const float* p = sxy + (size_t)r * 12;
        float sx = p[h], sy = p[4 + h], dn = p[8 + h];
        float t = fmaf(sx, w0, sy * w1) / (dn + 1e-16f) + bb;
        out1[(size_t)r * 256 + j] = t;
        s += t; q = fmaf(t, t, q);
    }
    atomicAdd(&bnsum[j], s);
    atomicAdd(&bnsq[j], q);
}

// ---------- Layer 2 GEMM with fused BN1+ELU on load ----------
__global__ void k_gemm2(const float* __restrict__ x2raw, const float* __restrict__ W2,
                        const float* __restrict__ bnsum, const float* __restrict__ bnsq,
                        const float* __restrict__ gamma, const float* __restrict__ beta,
                        float* __restrict__ g2, int N) {
    __shared__ float xs[16][256];
    int n0 = blockIdx.x * 16, tid = threadIdx.x;
    float mu = bnsum[tid] / N;
    float var = bnsq[tid] / N - mu * mu;
    float sc = rsqrtf(var + BN_EPS) * gamma[tid];
    float sh = beta[tid] - mu * sc;
    #pragma unroll
    for (int t = 0; t < 16; t++) {
        int n = n0 + t;
        float v = 0.f;
        if (n < N) {
            float y = fmaf(x2raw[(size_t)n * 256 + tid], sc, sh);
            v = y > 0.f ? y : (__expf(y) - 1.0f);
        }
        xs[t][tid] = v;
    }
    __syncthreads();
    int c = tid & 127, rb = (tid >> 7) * 8;
    float acc[8] = {0.f, 0.f, 0.f, 0.f, 0.f, 0.f, 0.f, 0.f};
    for (int k = 0; k < 256; k++) {
        float w = W2[k * 128 + c];
        #pragma unroll
        for (int r = 0; r < 8; r++) acc[r] = fmaf(xs[rb + r][k], w, acc[r]);
    }
    #pragma unroll
    for (int r = 0; r < 8; r++) {
        int n = n0 + rb + r;
        if (n < N) g2[(size_t)n * 128 + c] = acc[r];
    }
}

// alpha dots for layer 2: one wave per node
__global__ void k_alpha2(const float* __restrict__ g2, const float* __restrict__ asw,
                         const float* __restrict__ adw, float* __restrict__ as2,
                         float* __restrict__ ad2) {
    int n = blockIdx.x, l = threadIdx.x;  // 64 threads
    float g0 = g2[(size_t)n * 128 + l], g1 = g2[(size_t)n * 128 + 64 + l];
    float ps = fmaf(g0, asw[l], g1 * asw[64 + l]);
    float pd = fmaf(g0, adw[l], g1 * adw[64 + l]);
    for (int o = 32; o; o >>= 1) { ps += __shfl_down(ps, o); pd += __shfl_down(pd, o); }
    if (l == 0) { as2[n] = ps; ad2[n] = pd; }
}

// ---------- Layer 2 aggregation: weights staged in LDS, single pass ----------
__global__ void k_agg2(const int* __restrict__ rp, const int* __restrict__ esrc,
                       const float* __restrict__ as2, const float* __restrict__ ad2,
                       const float* __restrict__ g2, const float* __restrict__ b2,
                       float* __restrict__ out2) {
    __shared__ float ws[128];
    __shared__ int ssn[128];
    int n = blockIdx.x, j = threadIdx.x;  // 128 threads
    int beg = rp[n], end = rp[n + 1];
    float ad = ad2[n];
    float acc = 0.f, den = 0.f;
    for (int t0 = beg; t0 < end; t0 += 128) {
        int k = t0 + j;
        if (k < end) {
            int s = esrc[k];
            float e = as2[s] + ad;
            e = e > 0.f ? e : NEG_SLOPE * e;
            ws[j] = __expf(e);
            ssn[j] = s;
        }
        __syncthreads();
        int nt = min(128, end - t0);
        for (int k2 = 0; k2 < nt; k2++) {
            float w = ws[k2];
            den += w;
            acc = fmaf(w, g2[(size_t)ssn[k2] * 128 + j], acc);
        }
        __syncthreads();
    }
    out2[(size_t)n * 128 + j] = acc / (den + 1e-16f) + b2[j];
}

// ---------- BN stats ----------
__global__ void k_bnstats(const float* __restrict__ v, int N, int F,
                          float* __restrict__ sum, float* __restrict__ sq) {
    int j = threadIdx.x;
    int rows = (N + gridDim.x - 1) / gridDim.x;
    int r0 = blockIdx.x * rows, r1 = min(N, r0 + rows);
    float s = 0.f, q = 0.f;
    for (int r = r0; r < r1; r++) { float t = v[(size_t)r * F + j]; s += t; q = fmaf(t, t, q); }
    atomicAdd(&sum[j], s);
    atomicAdd(&sq[j], q);
}

// ---------- graph boundaries by binary search (batch is sorted) ----------
__global__ void k_gbounds(const int* __restrict__ batch, int N, int G, int* __restrict__ gb) {
    int g = blockIdx.x * blockDim.x + threadIdx.x;
    if (g > G) return;
    int lo = 0, hi = N;
    while (lo < hi) { int mid = (lo + hi) >> 1; if (batch[mid] < g) lo = mid + 1; else hi = mid; }
    gb[g] = lo;
}

// ---------- pooling: one block per graph, atomic-free, BN2+ELU+mean fused ----------
__global__ void k_poolg(const float* __restrict__ v, const int* __restrict__ gb,
                        const float* __restrict__ bnsum, const float* __restrict__ bnsq,
                        const float* __restrict__ gamma, const float* __restrict__ beta,
                        float* __restrict__ out, int N) {
    int g = blockIdx.x, j = threadIdx.x;  // 128
    float mu = bnsum[j] / N;
    float var = bnsq[j] / N - mu * mu;
    float sc = rsqrtf(var + BN_EPS) * gamma[j];
    float sh = beta[j] - mu * sc;
    int r0 = gb[g], r1 = gb[g + 1];
    float acc = 0.f;
    for (int r = r0; r < r1; r++) {
        float y = fmaf(v[(size_t)r * 128 + j], sc, sh);
        acc += y > 0.f ? y : (__expf(y) - 1.0f);
    }
    out[(size_t)g * 128 + j] = acc / fmaxf((float)(r1 - r0), 1.0f);
}

extern "C" void kernel_launch(void* const* d_in, const int* in_sizes, int n_in,
                              void* d_out, int out_size, void* d_ws, size_t ws_size,
                              hipStream_t stream) {
    const float* x     = (const float*)d_in[0];
    const int*   ei    = (const int*)d_in[1];
    const int*   batch = (const int*)d_in[2];
    const float* W1    = (const float*)d_in[4];
    const float* asw1  = (const float*)d_in[5];
    const float* adw1  = (const float*)d_in[6];
    const float* b1    = (const float*)d_in[7];
    const float* gamma1= (const float*)d_in[8];
    const float* beta1 = (const float*)d_in[9];
    const float* W2    = (const float*)d_in[10];
    const float* asw2  = (const float*)d_in[11];
    const float* adw2  = (const float*)d_in[12];
    const float* b2    = (const float*)d_in[13];
    const float* gamma2= (const float*)d_in[14];
    const float* beta2 = (const float*)d_in[15];
    float* out = (float*)d_out;

    const int N  = in_sizes[2];
    const int E  = in_sizes[1] / 2;
    const int E2 = E + N;
    const int G  = out_size / 128;

    char* ws = (char*)d_ws;
    size_t off = 0;
    auto A = [&](size_t bytes) { size_t o = off; off += (bytes + 255) & ~(size_t)255; return o; };
    float* out1  = (float*)(ws + A((size_t)N * 256 * 4));
    float* g2    = (float*)(ws + A((size_t)N * 128 * 4));
    float* out2  = (float*)(ws + A((size_t)N * 128 * 4));
    float* sxy   = (float*)(ws + A((size_t)N * 12 * 4));
    float* as2   = (float*)(ws + A((size_t)N * 4));
    float* ad2   = (float*)(ws + A((size_t)N * 4));
    float* coef  = (float*)(ws + A(16 * 4));
    float* bnsum = (float*)(ws + A(256 * 4));
    float* bnsq  = (float*)(ws + A(256 * 4));
    int*   gb    = (int*)(ws + A((size_t)(G + 1) * 4));
    int*   rp    = (int*)(ws + A((size_t)(N + 1) * 4));
    int*   cnt   = (int*)(ws + A((size_t)N * 4));
    int*   esrc  = (int*)(ws + A((size_t)E2 * 4));
    int*   bsums = (int*)(ws + A((size_t)((N + 1023) / 1024) * 4));

    const int nb = (N + 1023) / 1024;

    // fold attention vectors through W1 (tiny)
    k_coef<<<1, 256, 0, stream>>>(W1, asw1, adw1, coef);

    // CSR build (dst-keyed)
    hipMemsetAsync(cnt, 0, (size_t)N * 4, stream);
    k_deg<<<(E2 + 255) / 256, 256, 0, stream>>>(ei, E, E2, cnt);
    k_scan1<<<nb, 1024, 0, stream>>>(cnt, rp, bsums, N);
    k_scan2<<<1, 1, 0, stream>>>(bsums, nb, rp, N, E2);
    k_scan3<<<nb, 1024, 0, stream>>>(rp, bsums, N);
    hipMemsetAsync(cnt, 0, (size_t)N * 4, stream);
    k_scatter<<<(E2 + 255) / 256, 256, 0, stream>>>(ei, E, E2, rp, cnt, esrc);

    // graph boundaries (binary search over sorted batch) — replaces atomic histogram
    k_gbounds<<<(G + 1 + 255) / 256, 256, 0, stream>>>(batch, N, G, gb);

    // Layer 1: rank-2 aggregation, then epilogue + BN1 stats
    k_agg1r<<<(N + 255) / 256, 256, 0, stream>>>(rp, esrc, x, coef, sxy, N);
    hipMemsetAsync(bnsum, 0, 256 * 4, stream);
    hipMemsetAsync(bnsq, 0, 256 * 4, stream);
    k_out1<<<256, 256, 0, stream>>>(sxy, W1, b1, out1, bnsum, bnsq, N);

    // Layer 2 GEMM (BN1+ELU fused on load) + alpha dots
    k_gemm2<<<(N + 15) / 16, 256, 0, stream>>>(out1, W2, bnsum, bnsq, gamma1, beta1, g2, N);
    k_alpha2<<<N, 64, 0, stream>>>(g2, asw2, adw2, as2, ad2);

    // Layer 2 aggregation
    k_agg2<<<N, 128, 0, stream>>>(rp, esrc, as2, ad2, g2, b2, out2);

    // BN2 stats, then atomic-free pooling with fused BN2+ELU+mean
    hipMemsetAsync(bnsum, 0, 256 * 4, stream);
    hipMemsetAsync(bnsq, 0, 256 * 4, stream);
    k_bnstats<<<256, 128, 0, stream>>>(out2, N, 128, bnsum, bnsq);
    k_poolg<<<G, 128, 0, stream>>>(out2, gb, bnsum, bnsq, gamma2, beta2, out, N);
}

// Round 4
// 308.501 us; speedup vs baseline: 2.4100x; 1.3721x over previous
//
#include <hip/hip_runtime.h>
#include <hip/hip_bf16.h>

#define NEG_SLOPE 0.2f
#define BN_EPS 1e-5f

// ---------- tiny coefficient kernel: fold att vectors through W1 ----------
__global__ void k_coef(const float* __restrict__ W1, const float* __restrict__ asw,
                       const float* __restrict__ adw, float* __restrict__ coef) {
    int j = threadIdx.x;  // 256
    float w0 = W1[j], w1 = W1[256 + j], as = asw[j], ad = adw[j];
    float v0 = w0 * as, v1 = w1 * as, v2 = w0 * ad, v3 = w1 * ad;
    for (int o = 32; o; o >>= 1) {
        v0 += __shfl_down(v0, o); v1 += __shfl_down(v1, o);
        v2 += __shfl_down(v2, o); v3 += __shfl_down(v3, o);
    }
    if ((j & 63) == 0) {
        int h = j >> 6;
        coef[h * 4 + 0] = v0; coef[h * 4 + 1] = v1;
        coef[h * 4 + 2] = v2; coef[h * 4 + 3] = v3;
    }
}

// ---------- CSR build ----------
__global__ void k_deg(const int* __restrict__ ei, int E, int E2, int* __restrict__ cnt) {
    int i = blockIdx.x * blockDim.x + threadIdx.x;
    if (i >= E2) return;
    int d = (i < E) ? ei[E + i] : (i - E);
    atomicAdd(&cnt[d], 1);
}

__global__ void k_scan1(const int* __restrict__ deg, int* __restrict__ rp,
                        int* __restrict__ bsums, int n) {
    __shared__ int s[1024];
    int i = blockIdx.x * 1024 + threadIdx.x;
    int v = (i < n) ? deg[i] : 0;
    s[threadIdx.x] = v;
    __syncthreads();
    for (int o = 1; o < 1024; o <<= 1) {
        int t = (threadIdx.x >= o) ? s[threadIdx.x - o] : 0;
        __syncthreads();
        s[threadIdx.x] += t;
        __syncthreads();
    }
    if (i < n) rp[i] = s[threadIdx.x] - v;
    if (threadIdx.x == 1023) bsums[blockIdx.x] = s[1023];
}

__global__ void k_scan2(int* __restrict__ bsums, int nb, int* __restrict__ rp, int n, int total) {
    int run = 0;
    for (int b = 0; b < nb; b++) { int t = bsums[b]; bsums[b] = run; run += t; }
    rp[n] = total;
}

__global__ void k_scan3(int* __restrict__ rp, const int* __restrict__ bsums, int n) {
    int i = blockIdx.x * 1024 + threadIdx.x;
    if (i < n) rp[i] += bsums[blockIdx.x];
}

__global__ void k_scatter(const int* __restrict__ ei, int E, int E2,
                          const int* __restrict__ rp, int* __restrict__ cur,
                          int* __restrict__ esrc) {
    int i = blockIdx.x * blockDim.x + threadIdx.x;
    if (i >= E2) return;
    int s, d;
    if (i < E) { s = ei[i]; d = ei[E + i]; } else { s = d = i - E; }
    int pos = rp[d] + atomicAdd(&cur[d], 1);
    esrc[pos] = s;
}

// ---------- Layer 1 aggregation, rank-2 form: one THREAD per node ----------
__global__ void k_agg1r(const int* __restrict__ rp, const int* __restrict__ esrc,
                        const float* __restrict__ x, const float* __restrict__ coef,
                        float* __restrict__ sxy, int N) {
    int n = blockIdx.x * blockDim.x + threadIdx.x;
    if (n >= N) return;
    float c[16];
    #pragma unroll
    for (int i = 0; i < 16; i++) c[i] = coef[i];
    float x0n = x[2 * n], x1n = x[2 * n + 1];
    float ad[4], den[4], sx[4], sy[4];
    #pragma unroll
    for (int h = 0; h < 4; h++) {
        ad[h] = fmaf(x0n, c[h * 4 + 2], x1n * c[h * 4 + 3]);
        den[h] = 0.f; sx[h] = 0.f; sy[h] = 0.f;
    }
    int beg = rp[n], end = rp[n + 1];
    for (int k = beg; k < end; k++) {
        int s = esrc[k];
        float xs0 = x[2 * s], xs1 = x[2 * s + 1];
        #pragma unroll
        for (int h = 0; h < 4; h++) {
            float e = fmaf(xs0, c[h * 4 + 0], xs1 * c[h * 4 + 1]) + ad[h];
            e = e > 0.f ? e : NEG_SLOPE * e;
            float w = __expf(e);
            den[h] += w; sx[h] = fmaf(w, xs0, sx[h]); sy[h] = fmaf(w, xs1, sy[h]);
        }
    }
    float* o = sxy + (size_t)n * 12;
    #pragma unroll
    for (int h = 0; h < 4; h++) { o[h] = sx[h]; o[4 + h] = sy[h]; o[8 + h] = den[h]; }
}

// ---------- Layer 1 epilogue: rank-2 reconstruct + bias; fused BN1 stats ----------
__global__ void k_out1(const float* __restrict__ sxy, const float* __restrict__ W1,
                       const float* __restrict__ b1, float* __restrict__ out1,
                       float* __restrict__ bnsum, float* __restrict__ bnsq, int N) {
    int j = threadIdx.x;  // 256, channel
    int h = j >> 6;
    float w0 = W1[j], w1 = W1[256 + j], bb = b1[j];
    int rows = (N + gridDim.x - 1) / gridDim.x;
    int r0 = blockIdx.x * rows, r1 = min(N, r0 + rows);
    float s = 0.f, q = 0.f;
    for (int r = r0; r < r1; r++) {
        const float* p = sxy + (size_t)r * 12;
        float sx = p[h], sy = p[4 + h], dn = p[8 + h];
        float t = fmaf(sx, w0, sy * w1) / (dn + 1e-16f) + bb;
        out1[(size_t)r * 256 + j] = t;
        s += t; q = fmaf(t, t, q);
    }
    atomicAdd(&bnsum[j], s);
    atomicAdd(&bnsq[j], q);
}

// ---------- Layer 2 GEMM with fused BN1+ELU on load ----------
__global__ void k_gemm2(const float* __restrict__ x2raw, const float* __restrict__ W2,
                        const float* __restrict__ bnsum, const float* __restrict__ bnsq,
                        const float* __restrict__ gamma, const float* __restrict__ beta,
                        float* __restrict__ g2, int N) {
    __shared__ float xs[16][256];
    int n0 = blockIdx.x * 16, tid = threadIdx.x;
    float mu = bnsum[tid] / N;
    float var = bnsq[tid] / N - mu * mu;
    float sc = rsqrtf(var + BN_EPS) * gamma[tid];
    float sh = beta[tid] - mu * sc;
    #pragma unroll
    for (int t = 0; t < 16; t++) {
        int n = n0 + t;
        float v = 0.f;
        if (n < N) {
            float y = fmaf(x2raw[(size_t)n * 256 + tid], sc, sh);
            v = y > 0.f ? y : (__expf(y) - 1.0f);
        }
        xs[t][tid] = v;
    }
    __syncthreads();
    int c = tid & 127, rb = (tid >> 7) * 8;
    float acc[8] = {0.f, 0.f, 0.f, 0.f, 0.f, 0.f, 0.f, 0.f};
    for (int k = 0; k < 256; k++) {
        float w = W2[k * 128 + c];
        #pragma unroll
        for (int r = 0; r < 8; r++) acc[r] = fmaf(xs[rb + r][k], w, acc[r]);
    }
    #pragma unroll
    for (int r = 0; r < 8; r++) {
        int n = n0 + rb + r;
        if (n < N) g2[(size_t)n * 128 + c] = acc[r];
    }
}

// alpha dots for layer 2: one wave per node
__global__ void k_alpha2(const float* __restrict__ g2, const float* __restrict__ asw,
                         const float* __restrict__ adw, float* __restrict__ as2,
                         float* __restrict__ ad2) {
    int n = blockIdx.x, l = threadIdx.x;  // 64 threads
    float g0 = g2[(size_t)n * 128 + l], g1 = g2[(size_t)n * 128 + 64 + l];
    float ps = fmaf(g0, asw[l], g1 * asw[64 + l]);
    float pd = fmaf(g0, adw[l], g1 * adw[64 + l]);
    for (int o = 32; o; o >>= 1) { ps += __shfl_down(ps, o); pd += __shfl_down(pd, o); }
    if (l == 0) { as2[n] = ps; ad2[n] = pd; }
}

// ---------- Layer 2 aggregation: weights staged in LDS, single pass ----------
__global__ void k_agg2(const int* __restrict__ rp, const int* __restrict__ esrc,
                       const float* __restrict__ as2, const float* __restrict__ ad2,
                       const float* __restrict__ g2, const float* __restrict__ b2,
                       float* __restrict__ out2) {
    __shared__ float ws[128];
    __shared__ int ssn[128];
    int n = blockIdx.x, j = threadIdx.x;  // 128 threads
    int beg = rp[n], end = rp[n + 1];
    float ad = ad2[n];
    float acc = 0.f, den = 0.f;
    for (int t0 = beg; t0 < end; t0 += 128) {
        int k = t0 + j;
        if (k < end) {
            int s = esrc[k];
            float e = as2[s] + ad;
            e = e > 0.f ? e : NEG_SLOPE * e;
            ws[j] = __expf(e);
            ssn[j] = s;
        }
        __syncthreads();
        int nt = min(128, end - t0);
        for (int k2 = 0; k2 < nt; k2++) {
            float w = ws[k2];
            den += w;
            acc = fmaf(w, g2[(size_t)ssn[k2] * 128 + j], acc);
        }
        __syncthreads();
    }
    out2[(size_t)n * 128 + j] = acc / (den + 1e-16f) + b2[j];
}

// ---------- BN stats ----------
__global__ void k_bnstats(const float* __restrict__ v, int N, int F,
                          float* __restrict__ sum, float* __restrict__ sq) {
    int j = threadIdx.x;
    int rows = (N + gridDim.x - 1) / gridDim.x;
    int r0 = blockIdx.x * rows, r1 = min(N, r0 + rows);
    float s = 0.f, q = 0.f;
    for (int r = r0; r < r1; r++) { float t = v[(size_t)r * F + j]; s += t; q = fmaf(t, t, q); }
    atomicAdd(&sum[j], s);
    atomicAdd(&sq[j], q);
}

// ---------- graph boundaries by binary search (batch is sorted) ----------
__global__ void k_gbounds(const int* __restrict__ batch, int N, int G, int* __restrict__ gb) {
    int g = blockIdx.x * blockDim.x + threadIdx.x;
    if (g > G) return;
    int lo = 0, hi = N;
    while (lo < hi) { int mid = (lo + hi) >> 1; if (batch[mid] < g) lo = mid + 1; else hi = mid; }
    gb[g] = lo;
}

// ---------- pooling stage 1: row-parallel partial sums (BN2+ELU fused) ----------
__global__ void k_poolpart(const float* __restrict__ v, const int* __restrict__ batch,
                           const float* __restrict__ bnsum, const float* __restrict__ bnsq,
                           const float* __restrict__ gamma, const float* __restrict__ beta,
                           float* __restrict__ out, int N, int rowsPerBlock) {
    int j = threadIdx.x;  // 128
    float mu = bnsum[j] / N;
    float var = bnsq[j] / N - mu * mu;
    float sc = rsqrtf(var + BN_EPS) * gamma[j];
    float sh = beta[j] - mu * sc;
    int r0 = blockIdx.x * rowsPerBlock;
    if (r0 >= N) return;
    int r1 = min(N, r0 + rowsPerBlock);
    int curg = batch[r0];
    float acc = 0.f;
    for (int r = r0; r < r1; r++) {
        int g = batch[r];
        if (g != curg) {  // uniform branch (same for all threads)
            atomicAdd(&out[(size_t)curg * 128 + j], acc);
            curg = g; acc = 0.f;
        }
        float y = fmaf(v[(size_t)r * 128 + j], sc, sh);
        acc += y > 0.f ? y : (__expf(y) - 1.0f);
    }
    atomicAdd(&out[(size_t)curg * 128 + j], acc);
}

// ---------- pooling stage 2: divide by graph size ----------
__global__ void k_divg(float* __restrict__ out, const int* __restrict__ gb) {
    int g = blockIdx.x, j = threadIdx.x;  // 128
    out[(size_t)g * 128 + j] /= fmaxf((float)(gb[g + 1] - gb[g]), 1.0f);
}

extern "C" void kernel_launch(void* const* d_in, const int* in_sizes, int n_in,
                              void* d_out, int out_size, void* d_ws, size_t ws_size,
                              hipStream_t stream) {
    const float* x     = (const float*)d_in[0];
    const int*   ei    = (const int*)d_in[1];
    const int*   batch = (const int*)d_in[2];
    const float* W1    = (const float*)d_in[4];
    const float* asw1  = (const float*)d_in[5];
    const float* adw1  = (const float*)d_in[6];
    const float* b1    = (const float*)d_in[7];
    const float* gamma1= (const float*)d_in[8];
    const float* beta1 = (const float*)d_in[9];
    const float* W2    = (const float*)d_in[10];
    const float* asw2  = (const float*)d_in[11];
    const float* adw2  = (const float*)d_in[12];
    const float* b2    = (const float*)d_in[13];
    const float* gamma2= (const float*)d_in[14];
    const float* beta2 = (const float*)d_in[15];
    float* out = (float*)d_out;

    const int N  = in_sizes[2];
    const int E  = in_sizes[1] / 2;
    const int E2 = E + N;
    const int G  = out_size / 128;

    char* ws = (char*)d_ws;
    size_t off = 0;
    auto A = [&](size_t bytes) { size_t o = off; off += (bytes + 255) & ~(size_t)255; return o; };
    float* out1  = (float*)(ws + A((size_t)N * 256 * 4));
    float* g2    = (float*)(ws + A((size_t)N * 128 * 4));
    float* out2  = (float*)(ws + A((size_t)N * 128 * 4));
    float* sxy   = (float*)(ws + A((size_t)N * 12 * 4));
    float* as2   = (float*)(ws + A((size_t)N * 4));
    float* ad2   = (float*)(ws + A((size_t)N * 4));
    float* coef  = (float*)(ws + A(16 * 4));
    float* bnsum = (float*)(ws + A(256 * 4));
    float* bnsq  = (float*)(ws + A(256 * 4));
    int*   gb    = (int*)(ws + A((size_t)(G + 1) * 4));
    int*   rp    = (int*)(ws + A((size_t)(N + 1) * 4));
    int*   cnt   = (int*)(ws + A((size_t)N * 4));
    int*   esrc  = (int*)(ws + A((size_t)E2 * 4));
    int*   bsums = (int*)(ws + A((size_t)((N + 1023) / 1024) * 4));

    const int nb = (N + 1023) / 1024;

    // fold attention vectors through W1 (tiny)
    k_coef<<<1, 256, 0, stream>>>(W1, asw1, adw1, coef);

    // CSR build (dst-keyed)
    hipMemsetAsync(cnt, 0, (size_t)N * 4, stream);
    k_deg<<<(E2 + 255) / 256, 256, 0, stream>>>(ei, E, E2, cnt);
    k_scan1<<<nb, 1024, 0, stream>>>(cnt, rp, bsums, N);
    k_scan2<<<1, 1, 0, stream>>>(bsums, nb, rp, N, E2);
    k_scan3<<<nb, 1024, 0, stream>>>(rp, bsums, N);
    hipMemsetAsync(cnt, 0, (size_t)N * 4, stream);
    k_scatter<<<(E2 + 255) / 256, 256, 0, stream>>>(ei, E, E2, rp, cnt, esrc);

    // graph boundaries (binary search over sorted batch)
    k_gbounds<<<(G + 1 + 255) / 256, 256, 0, stream>>>(batch, N, G, gb);

    // Layer 1: rank-2 aggregation, then epilogue + BN1 stats
    k_agg1r<<<(N + 255) / 256, 256, 0, stream>>>(rp, esrc, x, coef, sxy, N);
    hipMemsetAsync(bnsum, 0, 256 * 4, stream);
    hipMemsetAsync(bnsq, 0, 256 * 4, stream);
    k_out1<<<512, 256, 0, stream>>>(sxy, W1, b1, out1, bnsum, bnsq, N);

    // Layer 2 GEMM (BN1+ELU fused on load) + alpha dots
    k_gemm2<<<(N + 15) / 16, 256, 0, stream>>>(out1, W2, bnsum, bnsq, gamma1, beta1, g2, N);
    k_alpha2<<<N, 64, 0, stream>>>(g2, asw2, adw2, as2, ad2);

    // Layer 2 aggregation
    k_agg2<<<N, 128, 0, stream>>>(rp, esrc, as2, ad2, g2, b2, out2);

    // BN2 stats, then row-parallel pooling with fused BN2+ELU, then divide
    hipMemsetAsync(bnsum, 0, 256 * 4, stream);
    hipMemsetAsync(bnsq, 0, 256 * 4, stream);
    k_bnstats<<<512, 128, 0, stream>>>(out2, N, 128, bnsum, bnsq);

    hipMemsetAsync(out, 0, (size_t)G * 128 * 4, stream);
    const int rowsPB = 64;
    k_poolpart<<<(N + rowsPB - 1) / rowsPB, 128, 0, stream>>>(out2, batch, bnsum, bnsq,
                                                              gamma2, beta2, out, N, rowsPB);
    k_divg<<<G, 128, 0, stream>>>(out, gb);
}

// Round 5
// 293.685 us; speedup vs baseline: 2.5316x; 1.0504x over previous
//
#include <hip/hip_runtime.h>
#include <hip/hip_bf16.h>

#define NEG_SLOPE 0.2f
#define BN_EPS 1e-5f

// ---------- tiny coefficient kernel: fold att vectors through W1 ----------
__global__ void k_coef(const float* __restrict__ W1, const float* __restrict__ asw,
                       const float* __restrict__ adw, float* __restrict__ coef) {
    int j = threadIdx.x;  // 256
    float w0 = W1[j], w1 = W1[256 + j], as = asw[j], ad = adw[j];
    float v0 = w0 * as, v1 = w1 * as, v2 = w0 * ad, v3 = w1 * ad;
    for (int o = 32; o; o >>= 1) {
        v0 += __shfl_down(v0, o); v1 += __shfl_down(v1, o);
        v2 += __shfl_down(v2, o); v3 += __shfl_down(v3, o);
    }
    if ((j & 63) == 0) {
        int h = j >> 6;
        coef[h * 4 + 0] = v0; coef[h * 4 + 1] = v1;
        coef[h * 4 + 2] = v2; coef[h * 4 + 3] = v3;
    }
}

// ---------- CSR build ----------
__global__ void k_deg(const int* __restrict__ ei, int E, int E2, int* __restrict__ cnt) {
    int i = blockIdx.x * blockDim.x + threadIdx.x;
    if (i >= E2) return;
    int d = (i < E) ? ei[E + i] : (i - E);
    atomicAdd(&cnt[d], 1);
}

__global__ void k_scan1(const int* __restrict__ deg, int* __restrict__ rp,
                        int* __restrict__ bsums, int n) {
    __shared__ int s[1024];
    int i = blockIdx.x * 1024 + threadIdx.x;
    int v = (i < n) ? deg[i] : 0;
    s[threadIdx.x] = v;
    __syncthreads();
    for (int o = 1; o < 1024; o <<= 1) {
        int t = (threadIdx.x >= o) ? s[threadIdx.x - o] : 0;
        __syncthreads();
        s[threadIdx.x] += t;
        __syncthreads();
    }
    if (i < n) rp[i] = s[threadIdx.x] - v;
    if (threadIdx.x == 1023) bsums[blockIdx.x] = s[1023];
}

__global__ void k_scan2(int* __restrict__ bsums, int nb, int* __restrict__ rp, int n, int total) {
    int run = 0;
    for (int b = 0; b < nb; b++) { int t = bsums[b]; bsums[b] = run; run += t; }
    rp[n] = total;
}

__global__ void k_scan3(int* __restrict__ rp, const int* __restrict__ bsums, int n) {
    int i = blockIdx.x * 1024 + threadIdx.x;
    if (i < n) rp[i] += bsums[blockIdx.x];
}

__global__ void k_scatter(const int* __restrict__ ei, int E, int E2,
                          const int* __restrict__ rp, int* __restrict__ cur,
                          int* __restrict__ esrc) {
    int i = blockIdx.x * blockDim.x + threadIdx.x;
    if (i >= E2) return;
    int s, d;
    if (i < E) { s = ei[i]; d = ei[E + i]; } else { s = d = i - E; }
    int pos = rp[d] + atomicAdd(&cur[d], 1);
    esrc[pos] = s;
}

// ---------- Layer 1 aggregation, rank-2 form: one THREAD per node ----------
__global__ void k_agg1r(const int* __restrict__ rp, const int* __restrict__ esrc,
                        const float* __restrict__ x, const float* __restrict__ coef,
                        float* __restrict__ sxy, int N) {
    int n = blockIdx.x * blockDim.x + threadIdx.x;
    if (n >= N) return;
    float c[16];
    #pragma unroll
    for (int i = 0; i < 16; i++) c[i] = coef[i];
    float x0n = x[2 * n], x1n = x[2 * n + 1];
    float ad[4], den[4], sx[4], sy[4];
    #pragma unroll
    for (int h = 0; h < 4; h++) {
        ad[h] = fmaf(x0n, c[h * 4 + 2], x1n * c[h * 4 + 3]);
        den[h] = 0.f; sx[h] = 0.f; sy[h] = 0.f;
    }
    int beg = rp[n], end = rp[n + 1];
    for (int k = beg; k < end; k++) {
        int s = esrc[k];
        float xs0 = x[2 * s], xs1 = x[2 * s + 1];
        #pragma unroll
        for (int h = 0; h < 4; h++) {
            float e = fmaf(xs0, c[h * 4 + 0], xs1 * c[h * 4 + 1]) + ad[h];
            e = e > 0.f ? e : NEG_SLOPE * e;
            float w = __expf(e);
            den[h] += w; sx[h] = fmaf(w, xs0, sx[h]); sy[h] = fmaf(w, xs1, sy[h]);
        }
    }
    float* o = sxy + (size_t)n * 12;
    #pragma unroll
    for (int h = 0; h < 4; h++) { o[h] = sx[h]; o[4 + h] = sy[h]; o[8 + h] = den[h]; }
}

// ---------- Layer 1 epilogue: rank-2 reconstruct + bias; fused BN1 stats ----------
__global__ void k_out1(const float* __restrict__ sxy, const float* __restrict__ W1,
                       const float* __restrict__ b1, float* __restrict__ out1,
                       float* __restrict__ bnsum, float* __restrict__ bnsq, int N) {
    int j = threadIdx.x;  // 256, channel
    int h = j >> 6;
    float w0 = W1[j], w1 = W1[256 + j], bb = b1[j];
    int rows = (N + gridDim.x - 1) / gridDim.x;
    int r0 = blockIdx.x * rows, r1 = min(N, r0 + rows);
    float s = 0.f, q = 0.f;
    for (int r = r0; r < r1; r++) {
        const float* p = sxy + (size_t)r * 12;
        float sx = p[h], sy = p[4 + h], dn = p[8 + h];
        float t = fmaf(sx, w0, sy * w1) / (dn + 1e-16f) + bb;
        out1[(size_t)r * 256 + j] = t;
        s += t; q = fmaf(t, t, q);
    }
    atomicAdd(&bnsum[j], s);
    atomicAdd(&bnsq[j], q);
}

// ---------- Layer 2 GEMM, register-tiled 64x128, fused BN1+ELU load + alpha2 dots ----------
// 256 threads: cg = tid&31 (4 cols each), rg = tid>>5 (8 rows each). K tiled by 128.
__global__ __launch_bounds__(256, 4) void k_gemm2(
        const float* __restrict__ x2raw, const float* __restrict__ W2,
        const float* __restrict__ bnsum, const float* __restrict__ bnsq,
        const float* __restrict__ gamma, const float* __restrict__ beta,
        const float* __restrict__ asw, const float* __restrict__ adw,
        float* __restrict__ g2, float* __restrict__ as2, float* __restrict__ ad2, int N) {
    __shared__ float xs[64][132];   // pad 132: 2 rows/wave -> worst 2-way (free)
    int tid = threadIdx.x;
    int n0 = blockIdx.x * 64;
    int cg = tid & 31, rg = tid >> 5;
    float acc[8][4];
    #pragma unroll
    for (int r = 0; r < 8; r++)
        #pragma unroll
        for (int c = 0; c < 4; c++) acc[r][c] = 0.f;

    for (int kt = 0; kt < 2; kt++) {
        // ---- stage 64x128 tile of BN1+ELU(x2raw) into LDS ----
        int c = tid & 127, half = tid >> 7;
        int gcol = kt * 128 + c;
        float mu = bnsum[gcol] / N;
        float var = bnsq[gcol] / N - mu * mu;
        float sc = rsqrtf(var + BN_EPS) * gamma[gcol];
        float sh = beta[gcol] - mu * sc;
        #pragma unroll
        for (int i = 0; i < 32; i++) {
            int r = half + 2 * i;
            int n = n0 + r;
            float v = 0.f;
            if (n < N) {
                float y = fmaf(x2raw[(size_t)n * 256 + gcol], sc, sh);
                v = y > 0.f ? y : (__expf(y) - 1.0f);
            }
            xs[r][c] = v;
        }
        __syncthreads();
        // ---- compute: 128 k-values in groups of 4 ----
        for (int k4 = 0; k4 < 32; k4++) {
            float4 wv[4];
            #pragma unroll
            for (int kk = 0; kk < 4; kk++)
                wv[kk] = *(const float4*)&W2[(size_t)(kt * 128 + k4 * 4 + kk) * 128 + cg * 4];
            #pragma unroll
            for (int r = 0; r < 8; r++) {
                float4 xv = *(const float4*)&xs[rg * 8 + r][k4 * 4];
                float xa0 = xv.x, xa1 = xv.y, xa2 = xv.z, xa3 = xv.w;
                acc[r][0] = fmaf(xa0, wv[0].x, acc[r][0]);
                acc[r][1] = fmaf(xa0, wv[0].y, acc[r][1]);
                acc[r][2] = fmaf(xa0, wv[0].z, acc[r][2]);
                acc[r][3] = fmaf(xa0, wv[0].w, acc[r][3]);
                acc[r][0] = fmaf(xa1, wv[1].x, acc[r][0]);
                acc[r][1] = fmaf(xa1, wv[1].y, acc[r][1]);
                acc[r][2] = fmaf(xa1, wv[1].z, acc[r][2]);
                acc[r][3] = fmaf(xa1, wv[1].w, acc[r][3]);
                acc[r][0] = fmaf(xa2, wv[2].x, acc[r][0]);
                acc[r][1] = fmaf(xa2, wv[2].y, acc[r][1]);
                acc[r][2] = fmaf(xa2, wv[2].z, acc[r][2]);
                acc[r][3] = fmaf(xa2, wv[2].w, acc[r][3]);
                acc[r][0] = fmaf(xa3, wv[3].x, acc[r][0]);
                acc[r][1] = fmaf(xa3, wv[3].y, acc[r][1]);
                acc[r][2] = fmaf(xa3, wv[3].z, acc[r][2]);
                acc[r][3] = fmaf(xa3, wv[3].w, acc[r][3]);
            }
        }
        __syncthreads();
    }

    // ---- epilogue: store g2 + fused alpha dots (half-wave shuffle reduce) ----
    float4 asv = *(const float4*)&asw[cg * 4];
    float4 adv = *(const float4*)&adw[cg * 4];
    #pragma unroll
    for (int r = 0; r < 8; r++) {
        int n = n0 + rg * 8 + r;
        float ps = acc[r][0] * asv.x + acc[r][1] * asv.y + acc[r][2] * asv.z + acc[r][3] * asv.w;
        float pd = acc[r][0] * adv.x + acc[r][1] * adv.y + acc[r][2] * adv.z + acc[r][3] * adv.w;
        #pragma unroll
        for (int o = 16; o; o >>= 1) { ps += __shfl_down(ps, o); pd += __shfl_down(pd, o); }
        if (n < N) {
            float4 ov = { acc[r][0], acc[r][1], acc[r][2], acc[r][3] };
            *(float4*)&g2[(size_t)n * 128 + cg * 4] = ov;
            if (cg == 0) { as2[n] = ps; ad2[n] = pd; }
        }
    }
}

// ---------- Layer 2 aggregation: wave per node, shuffle-broadcast, float2 gathers ----------
__global__ void k_agg2(const int* __restrict__ rp, const int* __restrict__ esrc,
                       const float* __restrict__ as2, const float* __restrict__ ad2,
                       const float* __restrict__ g2, const float* __restrict__ b2,
                       float* __restrict__ out2, int N) {
    int wid = threadIdx.x >> 6, lane = threadIdx.x & 63;
    int n = blockIdx.x * 4 + wid;
    if (n >= N) return;
    int beg = rp[n], end = rp[n + 1];
    float ad = ad2[n];
    float ax = 0.f, ay = 0.f, den = 0.f;
    for (int t0 = beg; t0 < end; t0 += 64) {
        int k = t0 + lane;
        int sl = 0; float wl = 0.f;
        if (k < end) {
            sl = esrc[k];
            float e = as2[sl] + ad;
            e = e > 0.f ? e : NEG_SLOPE * e;
            wl = __expf(e);
        }
        int nt = min(64, end - t0);
        for (int k2 = 0; k2 < nt; k2++) {
            float w = __shfl(wl, k2);
            int s = __shfl(sl, k2);
            float2 gv = ((const float2*)g2)[(size_t)s * 64 + lane];
            den += w;
            ax = fmaf(w, gv.x, ax);
            ay = fmaf(w, gv.y, ay);
        }
    }
    float inv = 1.f / (den + 1e-16f);
    float2 bv = ((const float2*)b2)[lane];
    float2 ov = { ax * inv + bv.x, ay * inv + bv.y };
    ((float2*)out2)[(size_t)n * 64 + lane] = ov;
}

// ---------- BN stats ----------
__global__ void k_bnstats(const float* __restrict__ v, int N, int F,
                          float* __restrict__ sum, float* __restrict__ sq) {
    int j = threadIdx.x;
    int rows = (N + gridDim.x - 1) / gridDim.x;
    int r0 = blockIdx.x * rows, r1 = min(N, r0 + rows);
    float s = 0.f, q = 0.f;
    for (int r = r0; r < r1; r++) { float t = v[(size_t)r * F + j]; s += t; q = fmaf(t, t, q); }
    atomicAdd(&sum[j], s);
    atomicAdd(&sq[j], q);
}

// ---------- graph boundaries by binary search (batch is sorted) ----------
__global__ void k_gbounds(const int* __restrict__ batch, int N, int G, int* __restrict__ gb) {
    int g = blockIdx.x * blockDim.x + threadIdx.x;
    if (g > G) return;
    int lo = 0, hi = N;
    while (lo < hi) { int mid = (lo + hi) >> 1; if (batch[mid] < g) lo = mid + 1; else hi = mid; }
    gb[g] = lo;
}

// ---------- pooling stage 1: row-parallel partial sums (BN2+ELU fused) ----------
__global__ void k_poolpart(const float* __restrict__ v, const int* __restrict__ batch,
                           const float* __restrict__ bnsum, const float* __restrict__ bnsq,
                           const float* __restrict__ gamma, const float* __restrict__ beta,
                           float* __restrict__ out, int N, int rowsPerBlock) {
    int j = threadIdx.x;  // 128
    float mu = bnsum[j] / N;
    float var = bnsq[j] / N - mu * mu;
    float sc = rsqrtf(var + BN_EPS) * gamma[j];
    float sh = beta[j] - mu * sc;
    int r0 = blockIdx.x * rowsPerBlock;
    if (r0 >= N) return;
    int r1 = min(N, r0 + rowsPerBlock);
    int curg = batch[r0];
    float acc = 0.f;
    for (int r = r0; r < r1; r++) {
        int g = batch[r];
        if (g != curg) {  // uniform branch
            atomicAdd(&out[(size_t)curg * 128 + j], acc);
            curg = g; acc = 0.f;
        }
        float y = fmaf(v[(size_t)r * 128 + j], sc, sh);
        acc += y > 0.f ? y : (__expf(y) - 1.0f);
    }
    atomicAdd(&out[(size_t)curg * 128 + j], acc);
}

// ---------- pooling stage 2: divide by graph size ----------
__global__ void k_divg(float* __restrict__ out, const int* __restrict__ gb) {
    int g = blockIdx.x, j = threadIdx.x;  // 128
    out[(size_t)g * 128 + j] /= fmaxf((float)(gb[g + 1] - gb[g]), 1.0f);
}

extern "C" void kernel_launch(void* const* d_in, const int* in_sizes, int n_in,
                              void* d_out, int out_size, void* d_ws, size_t ws_size,
                              hipStream_t stream) {
    const float* x     = (const float*)d_in[0];
    const int*   ei    = (const int*)d_in[1];
    const int*   batch = (const int*)d_in[2];
    const float* W1    = (const float*)d_in[4];
    const float* asw1  = (const float*)d_in[5];
    const float* adw1  = (const float*)d_in[6];
    const float* b1    = (const float*)d_in[7];
    const float* gamma1= (const float*)d_in[8];
    const float* beta1 = (const float*)d_in[9];
    const float* W2    = (const float*)d_in[10];
    const float* asw2  = (const float*)d_in[11];
    const float* adw2  = (const float*)d_in[12];
    const float* b2    = (const float*)d_in[13];
    const float* gamma2= (const float*)d_in[14];
    const float* beta2 = (const float*)d_in[15];
    float* out = (float*)d_out;

    const int N  = in_sizes[2];
    const int E  = in_sizes[1] / 2;
    const int E2 = E + N;
    const int G  = out_size / 128;

    char* ws = (char*)d_ws;
    size_t off = 0;
    auto A = [&](size_t bytes) { size_t o = off; off += (bytes + 255) & ~(size_t)255; return o; };
    float* out1  = (float*)(ws + A((size_t)N * 256 * 4));
    float* g2    = (float*)(ws + A((size_t)N * 128 * 4));
    float* out2  = (float*)(ws + A((size_t)N * 128 * 4));
    float* sxy   = (float*)(ws + A((size_t)N * 12 * 4));
    float* as2   = (float*)(ws + A((size_t)N * 4));
    float* ad2   = (float*)(ws + A((size_t)N * 4));
    float* coef  = (float*)(ws + A(16 * 4));
    float* bnsum = (float*)(ws + A(256 * 4));
    float* bnsq  = (float*)(ws + A(256 * 4));
    int*   gb    = (int*)(ws + A((size_t)(G + 1) * 4));
    int*   rp    = (int*)(ws + A((size_t)(N + 1) * 4));
    int*   cnt   = (int*)(ws + A((size_t)N * 4));
    int*   esrc  = (int*)(ws + A((size_t)E2 * 4));
    int*   bsums = (int*)(ws + A((size_t)((N + 1023) / 1024) * 4));

    const int nb = (N + 1023) / 1024;

    // fold attention vectors through W1 (tiny)
    k_coef<<<1, 256, 0, stream>>>(W1, asw1, adw1, coef);

    // CSR build (dst-keyed)
    hipMemsetAsync(cnt, 0, (size_t)N * 4, stream);
    k_deg<<<(E2 + 255) / 256, 256, 0, stream>>>(ei, E, E2, cnt);
    k_scan1<<<nb, 1024, 0, stream>>>(cnt, rp, bsums, N);
    k_scan2<<<1, 1, 0, stream>>>(bsums, nb, rp, N, E2);
    k_scan3<<<nb, 1024, 0, stream>>>(rp, bsums, N);
    hipMemsetAsync(cnt, 0, (size_t)N * 4, stream);
    k_scatter<<<(E2 + 255) / 256, 256, 0, stream>>>(ei, E, E2, rp, cnt, esrc);

    // graph boundaries (binary search over sorted batch)
    k_gbounds<<<(G + 1 + 255) / 256, 256, 0, stream>>>(batch, N, G, gb);

    // Layer 1: rank-2 aggregation, then epilogue + BN1 stats
    k_agg1r<<<(N + 255) / 256, 256, 0, stream>>>(rp, esrc, x, coef, sxy, N);
    hipMemsetAsync(bnsum, 0, 256 * 4, stream);
    hipMemsetAsync(bnsq, 0, 256 * 4, stream);
    k_out1<<<512, 256, 0, stream>>>(sxy, W1, b1, out1, bnsum, bnsq, N);

    // Layer 2 GEMM (BN1+ELU fused on load, alpha dots fused in epilogue)
    k_gemm2<<<(N + 63) / 64, 256, 0, stream>>>(out1, W2, bnsum, bnsq, gamma1, beta1,
                                               asw2, adw2, g2, as2, ad2, N);

    // Layer 2 aggregation (wave per node)
    k_agg2<<<(N + 3) / 4, 256, 0, stream>>>(rp, esrc, as2, ad2, g2, b2, out2, N);

    // BN2 stats, then row-parallel pooling with fused BN2+ELU, then divide
    hipMemsetAsync(bnsum, 0, 256 * 4, stream);
    hipMemsetAsync(bnsq, 0, 256 * 4, stream);
    k_bnstats<<<512, 128, 0, stream>>>(out2, N, 128, bnsum, bnsq);

    hipMemsetAsync(out, 0, (size_t)G * 128 * 4, stream);
    const int rowsPB = 64;
    k_poolpart<<<(N + rowsPB - 1) / rowsPB, 128, 0, stream>>>(out2, batch, bnsum, bnsq,
                                                              gamma2, beta2, out, N, rowsPB);
    k_divg<<<G, 128, 0, stream>>>(out, gb);
}

// Round 6
// 238.231 us; speedup vs baseline: 3.1208x; 1.2328x over previous
//
#include <hip/hip_runtime.h>
#include <hip/hip_bf16.h>

#define NEG_SLOPE 0.2f
#define BN_EPS 1e-5f

// ---------- tiny coefficient kernel: fold att vectors through W1 ----------
__global__ void k_coef(const float* __restrict__ W1, const float* __restrict__ asw,
                       const float* __restrict__ adw, float* __restrict__ coef) {
    int j = threadIdx.x;  // 256
    float w0 = W1[j], w1 = W1[256 + j], as = asw[j], ad = adw[j];
    float v0 = w0 * as, v1 = w1 * as, v2 = w0 * ad, v3 = w1 * ad;
    for (int o = 32; o; o >>= 1) {
        v0 += __shfl_down(v0, o); v1 += __shfl_down(v1, o);
        v2 += __shfl_down(v2, o); v3 += __shfl_down(v3, o);
    }
    if ((j & 63) == 0) {
        int h = j >> 6;
        coef[h * 4 + 0] = v0; coef[h * 4 + 1] = v1;
        coef[h * 4 + 2] = v2; coef[h * 4 + 3] = v3;
    }
}

// ---------- CSR build ----------
__global__ void k_deg(const int* __restrict__ ei, int E, int E2, int* __restrict__ cnt) {
    int i = blockIdx.x * blockDim.x + threadIdx.x;
    if (i >= E2) return;
    int d = (i < E) ? ei[E + i] : (i - E);
    atomicAdd(&cnt[d], 1);
}

__global__ void k_scan1(const int* __restrict__ deg, int* __restrict__ rp,
                        int* __restrict__ bsums, int n) {
    __shared__ int s[1024];
    int i = blockIdx.x * 1024 + threadIdx.x;
    int v = (i < n) ? deg[i] : 0;
    s[threadIdx.x] = v;
    __syncthreads();
    for (int o = 1; o < 1024; o <<= 1) {
        int t = (threadIdx.x >= o) ? s[threadIdx.x - o] : 0;
        __syncthreads();
        s[threadIdx.x] += t;
        __syncthreads();
    }
    if (i < n) rp[i] = s[threadIdx.x] - v;
    if (threadIdx.x == 1023) bsums[blockIdx.x] = s[1023];
}

__global__ void k_scan2(int* __restrict__ bsums, int nb, int* __restrict__ rp, int n, int total) {
    int run = 0;
    for (int b = 0; b < nb; b++) { int t = bsums[b]; bsums[b] = run; run += t; }
    rp[n] = total;
}

__global__ void k_scan3(int* __restrict__ rp, const int* __restrict__ bsums, int n) {
    int i = blockIdx.x * 1024 + threadIdx.x;
    if (i < n) rp[i] += bsums[blockIdx.x];
}

__global__ void k_scatter(const int* __restrict__ ei, int E, int E2,
                          const int* __restrict__ rp, int* __restrict__ cur,
                          int* __restrict__ esrc) {
    int i = blockIdx.x * blockDim.x + threadIdx.x;
    if (i >= E2) return;
    int s, d;
    if (i < E) { s = ei[i]; d = ei[E + i]; } else { s = d = i - E; }
    int pos = rp[d] + atomicAdd(&cur[d], 1);
    esrc[pos] = s;
}

// ---------- Layer 1 aggregation, rank-2 form: one THREAD per node ----------
// emits per node: u[4], v[4]  (softmax-normalized weighted sums of x0,x1 per head)
__global__ void k_agg1r(const int* __restrict__ rp, const int* __restrict__ esrc,
                        const float* __restrict__ x, const float* __restrict__ coef,
                        float* __restrict__ uv, int N) {
    int n = blockIdx.x * blockDim.x + threadIdx.x;
    if (n >= N) return;
    float c[16];
    #pragma unroll
    for (int i = 0; i < 16; i++) c[i] = coef[i];
    float x0n = x[2 * n], x1n = x[2 * n + 1];
    float ad[4], den[4], sx[4], sy[4];
    #pragma unroll
    for (int h = 0; h < 4; h++) {
        ad[h] = fmaf(x0n, c[h * 4 + 2], x1n * c[h * 4 + 3]);
        den[h] = 0.f; sx[h] = 0.f; sy[h] = 0.f;
    }
    int beg = rp[n], end = rp[n + 1];
    for (int k = beg; k < end; k++) {
        int s = esrc[k];
        float xs0 = x[2 * s], xs1 = x[2 * s + 1];
        #pragma unroll
        for (int h = 0; h < 4; h++) {
            float e = fmaf(xs0, c[h * 4 + 0], xs1 * c[h * 4 + 1]) + ad[h];
            e = e > 0.f ? e : NEG_SLOPE * e;
            float w = __expf(e);
            den[h] += w; sx[h] = fmaf(w, xs0, sx[h]); sy[h] = fmaf(w, xs1, sy[h]);
        }
    }
    float* o = uv + (size_t)n * 8;
    #pragma unroll
    for (int h = 0; h < 4; h++) {
        float inv = 1.f / (den[h] + 1e-16f);
        o[h] = sx[h] * inv; o[4 + h] = sy[h] * inv;
    }
}

// ---------- BN1 stats, analytic: reduce 20 per-head scalars over uv ----------
// stats[0..3]=Su, [4..7]=Sv, [8..11]=Suu, [12..15]=Svv, [16..19]=Suv
__global__ void k_stats1(const float* __restrict__ uv, float* __restrict__ stats, int N) {
    __shared__ float s[4][20];
    int tid = threadIdx.x, lane = tid & 63, wid = tid >> 6;
    int rows = (N + gridDim.x - 1) / gridDim.x;
    int r0 = blockIdx.x * rows, r1 = min(N, r0 + rows);
    float a[20];
    #pragma unroll
    for (int i = 0; i < 20; i++) a[i] = 0.f;
    for (int r = r0 + tid; r < r1; r += blockDim.x) {
        const float4* p = (const float4*)(uv + (size_t)r * 8);
        float4 u4 = p[0], v4 = p[1];
        float uu[4] = {u4.x, u4.y, u4.z, u4.w};
        float vv[4] = {v4.x, v4.y, v4.z, v4.w};
        #pragma unroll
        for (int h = 0; h < 4; h++) {
            a[h] += uu[h]; a[4 + h] += vv[h];
            a[8 + h] = fmaf(uu[h], uu[h], a[8 + h]);
            a[12 + h] = fmaf(vv[h], vv[h], a[12 + h]);
            a[16 + h] = fmaf(uu[h], vv[h], a[16 + h]);
        }
    }
    #pragma unroll
    for (int i = 0; i < 20; i++)
        for (int o = 32; o; o >>= 1) a[i] += __shfl_down(a[i], o);
    if (lane == 0)
        #pragma unroll
        for (int i = 0; i < 20; i++) s[wid][i] = a[i];
    __syncthreads();
    if (tid < 20) {
        float t = s[0][tid] + s[1][tid] + s[2][tid] + s[3][tid];
        atomicAdd(&stats[tid], t);
    }
}

// ---------- fold BN1(analytic)+bias+W1 into per-column affine A0,A1,A2 ----------
// t[n,j] = w0*u + w1*v + b ; xs = ELU(sc*t + sh) = ELU(A0*u + A1*v + A2)
__global__ void k_bn1coef(const float* __restrict__ stats, const float* __restrict__ W1,
                          const float* __restrict__ b1, const float* __restrict__ gamma,
                          const float* __restrict__ beta, float* __restrict__ abc, int N) {
    int j = threadIdx.x;  // 256
    int h = j >> 6;
    float w0 = W1[j], w1 = W1[256 + j], b = b1[j];
    float Su = stats[h], Sv = stats[4 + h], Suu = stats[8 + h], Svv = stats[12 + h], Suv = stats[16 + h];
    float fN = (float)N;
    float lin = fmaf(w0, Su, w1 * Sv);                     // sum of (t-b)
    float mean = lin / fN + b;
    float sq = w0 * w0 * Suu + w1 * w1 * Svv + 2.f * w0 * w1 * Suv + 2.f * b * lin + fN * b * b;
    float var = sq / fN - mean * mean;
    float sc = rsqrtf(var + BN_EPS) * gamma[j];
    float sh = beta[j] - mean * sc;
    abc[j] = sc * w0;
    abc[256 + j] = sc * w1;
    abc[512 + j] = fmaf(sc, b, sh);
}

// ---------- Layer 2 GEMM, register-tiled 64x128; input reconstructed from uv ----------
// 256 threads: cg = tid&31 (4 cols each), rg = tid>>5 (8 rows each). K tiled by 128.
__global__ __launch_bounds__(256, 2) void k_gemm2(
        const float* __restrict__ uv, const float* __restrict__ abc,
        const float* __restrict__ W2,
        const float* __restrict__ asw, const float* __restrict__ adw,
        float* __restrict__ g2, float* __restrict__ as2, float* __restrict__ ad2, int N) {
    __shared__ float xs[64][132];
    __shared__ float uvs[64][8];
    int tid = threadIdx.x;
    int n0 = blockIdx.x * 64;
    int cg = tid & 31, rg = tid >> 5;

    // stage uv tile (64 rows x 8) once
    {
        int r = tid >> 2, e2 = tid & 3;
        int n = n0 + r;
        float2 t = (n < N) ? ((const float2*)uv)[(size_t)n * 4 + e2] : make_float2(0.f, 0.f);
        uvs[r][e2 * 2] = t.x; uvs[r][e2 * 2 + 1] = t.y;
    }

    float acc[8][4];
    #pragma unroll
    for (int r = 0; r < 8; r++)
        #pragma unroll
        for (int c = 0; c < 4; c++) acc[r][c] = 0.f;

    for (int kt = 0; kt < 2; kt++) {
        __syncthreads();
        // ---- reconstruct+BN1+ELU staging: 64x128 tile ----
        int c = tid & 127, half = tid >> 7;
        int gcol = kt * 128 + c;
        int h = gcol >> 6;
        float a0 = abc[gcol], a1 = abc[256 + gcol], a2 = abc[512 + gcol];
        #pragma unroll
        for (int i = 0; i < 32; i++) {
            int r = half + 2 * i;
            float y = fmaf(a0, uvs[r][h], fmaf(a1, uvs[r][4 + h], a2));
            xs[r][c] = y > 0.f ? y : (__expf(y) - 1.0f);
        }
        __syncthreads();
        // ---- compute: 128 k-values in groups of 4 ----
        for (int k4 = 0; k4 < 32; k4++) {
            float4 wv[4];
            #pragma unroll
            for (int kk = 0; kk < 4; kk++)
                wv[kk] = *(const float4*)&W2[(size_t)(kt * 128 + k4 * 4 + kk) * 128 + cg * 4];
            #pragma unroll
            for (int r = 0; r < 8; r++) {
                float4 xv = *(const float4*)&xs[rg * 8 + r][k4 * 4];
                acc[r][0] = fmaf(xv.x, wv[0].x, acc[r][0]);
                acc[r][1] = fmaf(xv.x, wv[0].y, acc[r][1]);
                acc[r][2] = fmaf(xv.x, wv[0].z, acc[r][2]);
                acc[r][3] = fmaf(xv.x, wv[0].w, acc[r][3]);
                acc[r][0] = fmaf(xv.y, wv[1].x, acc[r][0]);
                acc[r][1] = fmaf(xv.y, wv[1].y, acc[r][1]);
                acc[r][2] = fmaf(xv.y, wv[1].z, acc[r][2]);
                acc[r][3] = fmaf(xv.y, wv[1].w, acc[r][3]);
                acc[r][0] = fmaf(xv.z, wv[2].x, acc[r][0]);
                acc[r][1] = fmaf(xv.z, wv[2].y, acc[r][1]);
                acc[r][2] = fmaf(xv.z, wv[2].z, acc[r][2]);
                acc[r][3] = fmaf(xv.z, wv[2].w, acc[r][3]);
                acc[r][0] = fmaf(xv.w, wv[3].x, acc[r][0]);
                acc[r][1] = fmaf(xv.w, wv[3].y, acc[r][1]);
                acc[r][2] = fmaf(xv.w, wv[3].z, acc[r][2]);
                acc[r][3] = fmaf(xv.w, wv[3].w, acc[r][3]);
            }
        }
    }

    // ---- epilogue: store g2 + fused alpha dots (half-wave shuffle reduce) ----
    float4 asv = *(const float4*)&asw[cg * 4];
    float4 adv = *(const float4*)&adw[cg * 4];
    #pragma unroll
    for (int r = 0; r < 8; r++) {
        int n = n0 + rg * 8 + r;
        float ps = acc[r][0] * asv.x + acc[r][1] * asv.y + acc[r][2] * asv.z + acc[r][3] * asv.w;
        float pd = acc[r][0] * adv.x + acc[r][1] * adv.y + acc[r][2] * adv.z + acc[r][3] * adv.w;
        #pragma unroll
        for (int o = 16; o; o >>= 1) { ps += __shfl_down(ps, o); pd += __shfl_down(pd, o); }
        if (n < N) {
            float4 ov = { acc[r][0], acc[r][1], acc[r][2], acc[r][3] };
            *(float4*)&g2[(size_t)n * 128 + cg * 4] = ov;
            if (cg == 0) { as2[n] = ps; ad2[n] = pd; }
        }
    }
}

// ---------- Layer 2 aggregation: wave per node, shuffle-broadcast, float2 gathers ----------
__global__ void k_agg2(const int* __restrict__ rp, const int* __restrict__ esrc,
                       const float* __restrict__ as2, const float* __restrict__ ad2,
                       const float* __restrict__ g2, const float* __restrict__ b2,
                       float* __restrict__ out2, int N) {
    int wid = threadIdx.x >> 6, lane = threadIdx.x & 63;
    int n = blockIdx.x * 4 + wid;
    if (n >= N) return;
    int beg = rp[n], end = rp[n + 1];
    float ad = ad2[n];
    float ax = 0.f, ay = 0.f, den = 0.f;
    for (int t0 = beg; t0 < end; t0 += 64) {
        int k = t0 + lane;
        int sl = 0; float wl = 0.f;
        if (k < end) {
            sl = esrc[k];
            float e = as2[sl] + ad;
            e = e > 0.f ? e : NEG_SLOPE * e;
            wl = __expf(e);
        }
        int nt = min(64, end - t0);
        for (int k2 = 0; k2 < nt; k2++) {
            float w = __shfl(wl, k2);
            int s = __shfl(sl, k2);
            float2 gv = ((const float2*)g2)[(size_t)s * 64 + lane];
            den += w;
            ax = fmaf(w, gv.x, ax);
            ay = fmaf(w, gv.y, ay);
        }
    }
    float inv = 1.f / (den + 1e-16f);
    float2 bv = ((const float2*)b2)[lane];
    float2 ov = { ax * inv + bv.x, ay * inv + bv.y };
    ((float2*)out2)[(size_t)n * 64 + lane] = ov;
}

// ---------- BN stats ----------
__global__ void k_bnstats(const float* __restrict__ v, int N, int F,
                          float* __restrict__ sum, float* __restrict__ sq) {
    int j = threadIdx.x;
    int rows = (N + gridDim.x - 1) / gridDim.x;
    int r0 = blockIdx.x * rows, r1 = min(N, r0 + rows);
    float s = 0.f, q = 0.f;
    for (int r = r0; r < r1; r++) { float t = v[(size_t)r * F + j]; s += t; q = fmaf(t, t, q); }
    atomicAdd(&sum[j], s);
    atomicAdd(&sq[j], q);
}

// ---------- graph boundaries by binary search (batch is sorted) ----------
__global__ void k_gbounds(const int* __restrict__ batch, int N, int G, int* __restrict__ gb) {
    int g = blockIdx.x * blockDim.x + threadIdx.x;
    if (g > G) return;
    int lo = 0, hi = N;
    while (lo < hi) { int mid = (lo + hi) >> 1; if (batch[mid] < g) lo = mid + 1; else hi = mid; }
    gb[g] = lo;
}

// ---------- pooling stage 1: row-parallel partial sums (BN2+ELU fused) ----------
__global__ void k_poolpart(const float* __restrict__ v, const int* __restrict__ batch,
                           const float* __restrict__ bnsum, const float* __restrict__ bnsq,
                           const float* __restrict__ gamma, const float* __restrict__ beta,
                           float* __restrict__ out, int N, int rowsPerBlock) {
    int j = threadIdx.x;  // 128
    float mu = bnsum[j] / N;
    float var = bnsq[j] / N - mu * mu;
    float sc = rsqrtf(var + BN_EPS) * gamma[j];
    float sh = beta[j] - mu * sc;
    int r0 = blockIdx.x * rowsPerBlock;
    if (r0 >= N) return;
    int r1 = min(N, r0 + rowsPerBlock);
    int curg = batch[r0];
    float acc = 0.f;
    for (int r = r0; r < r1; r++) {
        int g = batch[r];
        if (g != curg) {  // uniform branch
            atomicAdd(&out[(size_t)curg * 128 + j], acc);
            curg = g; acc = 0.f;
        }
        float y = fmaf(v[(size_t)r * 128 + j], sc, sh);
        acc += y > 0.f ? y : (__expf(y) - 1.0f);
    }
    atomicAdd(&out[(size_t)curg * 128 + j], acc);
}

// ---------- pooling stage 2: divide by graph size ----------
__global__ void k_divg(float* __restrict__ out, const int* __restrict__ gb) {
    int g = blockIdx.x, j = threadIdx.x;  // 128
    out[(size_t)g * 128 + j] /= fmaxf((float)(gb[g + 1] - gb[g]), 1.0f);
}

extern "C" void kernel_launch(void* const* d_in, const int* in_sizes, int n_in,
                              void* d_out, int out_size, void* d_ws, size_t ws_size,
                              hipStream_t stream) {
    const float* x     = (const float*)d_in[0];
    const int*   ei    = (const int*)d_in[1];
    const int*   batch = (const int*)d_in[2];
    const float* W1    = (const float*)d_in[4];
    const float* asw1  = (const float*)d_in[5];
    const float* adw1  = (const float*)d_in[6];
    const float* b1    = (const float*)d_in[7];
    const float* gamma1= (const float*)d_in[8];
    const float* beta1 = (const float*)d_in[9];
    const float* W2    = (const float*)d_in[10];
    const float* asw2  = (const float*)d_in[11];
    const float* adw2  = (const float*)d_in[12];
    const float* b2    = (const float*)d_in[13];
    const float* gamma2= (const float*)d_in[14];
    const float* beta2 = (const float*)d_in[15];
    float* out = (float*)d_out;

    const int N  = in_sizes[2];
    const int E  = in_sizes[1] / 2;
    const int E2 = E + N;
    const int G  = out_size / 128;

    char* ws = (char*)d_ws;
    size_t off = 0;
    auto A = [&](size_t bytes) { size_t o = off; off += (bytes + 255) & ~(size_t)255; return o; };
    float* g2    = (float*)(ws + A((size_t)N * 128 * 4));
    float* out2  = (float*)(ws + A((size_t)N * 128 * 4));
    float* uv    = (float*)(ws + A((size_t)N * 8 * 4));
    float* as2   = (float*)(ws + A((size_t)N * 4));
    float* ad2   = (float*)(ws + A((size_t)N * 4));
    float* coef  = (float*)(ws + A(16 * 4));
    float* stats = (float*)(ws + A(20 * 4));
    float* abc   = (float*)(ws + A(768 * 4));
    float* bnsum = (float*)(ws + A(256 * 4));
    float* bnsq  = (float*)(ws + A(256 * 4));
    int*   gb    = (int*)(ws + A((size_t)(G + 1) * 4));
    int*   rp    = (int*)(ws + A((size_t)(N + 1) * 4));
    int*   cnt   = (int*)(ws + A((size_t)N * 4));
    int*   esrc  = (int*)(ws + A((size_t)E2 * 4));
    int*   bsums = (int*)(ws + A((size_t)((N + 1023) / 1024) * 4));

    const int nb = (N + 1023) / 1024;

    // fold attention vectors through W1 (tiny)
    k_coef<<<1, 256, 0, stream>>>(W1, asw1, adw1, coef);

    // CSR build (dst-keyed)
    hipMemsetAsync(cnt, 0, (size_t)N * 4, stream);
    k_deg<<<(E2 + 255) / 256, 256, 0, stream>>>(ei, E, E2, cnt);
    k_scan1<<<nb, 1024, 0, stream>>>(cnt, rp, bsums, N);
    k_scan2<<<1, 1, 0, stream>>>(bsums, nb, rp, N, E2);
    k_scan3<<<nb, 1024, 0, stream>>>(rp, bsums, N);
    hipMemsetAsync(cnt, 0, (size_t)N * 4, stream);
    k_scatter<<<(E2 + 255) / 256, 256, 0, stream>>>(ei, E, E2, rp, cnt, esrc);

    // graph boundaries (binary search over sorted batch)
    k_gbounds<<<(G + 1 + 255) / 256, 256, 0, stream>>>(batch, N, G, gb);

    // Layer 1: rank-2 aggregation -> uv; analytic BN1 stats; fold into affine
    k_agg1r<<<(N + 255) / 256, 256, 0, stream>>>(rp, esrc, x, coef, uv, N);
    hipMemsetAsync(stats, 0, 20 * 4, stream);
    k_stats1<<<64, 256, 0, stream>>>(uv, stats, N);
    k_bn1coef<<<1, 256, 0, stream>>>(stats, W1, b1, gamma1, beta1, abc, N);

    // Layer 2 GEMM (input reconstructed from uv, BN1+ELU fused; alpha dots in epilogue)
    k_gemm2<<<(N + 63) / 64, 256, 0, stream>>>(uv, abc, W2, asw2, adw2, g2, as2, ad2, N);

    // Layer 2 aggregation (wave per node)
    k_agg2<<<(N + 3) / 4, 256, 0, stream>>>(rp, esrc, as2, ad2, g2, b2, out2, N);

    // BN2 stats, then row-parallel pooling with fused BN2+ELU, then divide
    hipMemsetAsync(bnsum, 0, 256 * 4, stream);
    hipMemsetAsync(bnsq, 0, 256 * 4, stream);
    k_bnstats<<<512, 128, 0, stream>>>(out2, N, 128, bnsum, bnsq);

    hipMemsetAsync(out, 0, (size_t)G * 128 * 4, stream);
    const int rowsPB = 64;
    k_poolpart<<<(N + rowsPB - 1) / rowsPB, 128, 0, stream>>>(out2, batch, bnsum, bnsq,
                                                              gamma2, beta2, out, N, rowsPB);
    k_divg<<<G, 128, 0, stream>>>(out, gb);
}